// Round 1
// baseline (1932.134 us; speedup 1.0000x reference)
//
#include <hip/hip_runtime.h>

#define T_   91
#define D_   256
#define H_   4
#define DH_  64
#define NA_  128
#define NRG_ 1024
#define KEXP_ 4

static constexpr float NEGV = -1e10f;

#define BM 64
#define BN 64
#define BKK 16

// ---------------------------------------------------------------------------
// Per-row LayerNorm stats for agent (rows [0, NA*T)) and rg (rows [NA*T, ...))
// mu/rs laid out contiguously: agent rows first, then rg rows.
// ---------------------------------------------------------------------------
__global__ void ln_stats(const float* __restrict__ agent, const float* __restrict__ rg,
                         float* __restrict__ mu, float* __restrict__ rs) {
    int row = blockIdx.x;
    int tid = threadIdx.x;
    const float* src = (row < NA_ * T_) ? (agent + (size_t)row * D_)
                                        : (rg + (size_t)(row - NA_ * T_) * D_);
    float x = src[tid];
    __shared__ float red[256];
    red[tid] = x;
    __syncthreads();
    for (int s = 128; s > 0; s >>= 1) {
        if (tid < s) red[tid] += red[tid + s];
        __syncthreads();
    }
    float mean = red[0] * (1.0f / 256.0f);
    __syncthreads();
    float dx = x - mean;
    red[tid] = dx * dx;
    __syncthreads();
    for (int s = 128; s > 0; s >>= 1) {
        if (tid < s) red[tid] += red[tid + s];
        __syncthreads();
    }
    if (tid == 0) {
        mu[row] = mean;
        rs[row] = rsqrtf(red[0] * (1.0f / 256.0f) + 1e-5f);
    }
}

// ---------------------------------------------------------------------------
// Generic fp32 tiled GEMM: out = epilogue(A_n @ W + bias)
//   A: M x K row-major (optionally LayerNormed inline via mu/rs/lng/lnb)
//   W: K x N row-major
// mode 0: relu, row-major out (M x N)
// mode 1: relu, transposed (t,h,r,d) out with NN=NRG   (K / V projections)
// mode 2: relu * qscale[d], transposed out with NN=NA  (Q projection)
// mode 3: relu + LayerNorm(resid) residual add, row-major out (Y2 + agent_n)
//         (mu/rs here apply to resid rows since ln_a == 0 in this mode)
// ---------------------------------------------------------------------------
__global__ void gemm_fused(const float* __restrict__ A, const float* __restrict__ W,
                           const float* __restrict__ bias,
                           const float* __restrict__ mu, const float* __restrict__ rs,
                           const float* __restrict__ lng, const float* __restrict__ lnb,
                           const float* __restrict__ qscale,
                           const float* __restrict__ resid,
                           float* __restrict__ out,
                           int M, int N, int K, int mode, int ln_a) {
    __shared__ float As[BM][BKK + 1];
    __shared__ float Bs[BKK][BN];
    int bm = blockIdx.x * BM;
    int bn = blockIdx.y * BN;
    int tid = threadIdx.x;
    int tx = tid % 16, ty = tid / 16;
    float acc[4][4] = {};

    for (int k0 = 0; k0 < K; k0 += BKK) {
        for (int e = tid; e < BM * BKK; e += 256) {
            int r = e / BKK, c = e % BKK;
            int m = bm + r;
            float v = A[(size_t)m * K + k0 + c];
            if (ln_a) v = (v - mu[m]) * rs[m] * lng[k0 + c] + lnb[k0 + c];
            As[r][c] = v;
        }
        for (int e = tid; e < BKK * BN; e += 256) {
            int r = e / BN, c = e % BN;
            Bs[r][c] = W[(size_t)(k0 + r) * N + bn + c];
        }
        __syncthreads();
#pragma unroll
        for (int k = 0; k < BKK; ++k) {
            float a0 = As[ty * 4 + 0][k];
            float a1 = As[ty * 4 + 1][k];
            float a2 = As[ty * 4 + 2][k];
            float a3 = As[ty * 4 + 3][k];
            float b0 = Bs[k][tx * 4 + 0];
            float b1 = Bs[k][tx * 4 + 1];
            float b2 = Bs[k][tx * 4 + 2];
            float b3 = Bs[k][tx * 4 + 3];
            acc[0][0] += a0 * b0; acc[0][1] += a0 * b1; acc[0][2] += a0 * b2; acc[0][3] += a0 * b3;
            acc[1][0] += a1 * b0; acc[1][1] += a1 * b1; acc[1][2] += a1 * b2; acc[1][3] += a1 * b3;
            acc[2][0] += a2 * b0; acc[2][1] += a2 * b1; acc[2][2] += a2 * b2; acc[2][3] += a2 * b3;
            acc[3][0] += a3 * b0; acc[3][1] += a3 * b1; acc[3][2] += a3 * b2; acc[3][3] += a3 * b3;
        }
        __syncthreads();
    }

#pragma unroll
    for (int i = 0; i < 4; ++i) {
#pragma unroll
        for (int j = 0; j < 4; ++j) {
            int m = bm + ty * 4 + i;
            int n = bn + tx * 4 + j;
            float v = acc[i][j] + bias[n];
            v = fmaxf(v, 0.0f);
            if (mode == 2) v *= qscale[n & (DH_ - 1)];
            if (mode == 3) {
                float a = resid[(size_t)m * D_ + n];
                a = (a - mu[m]) * rs[m] * lng[n] + lnb[n];
                v += a;
            }
            if (mode == 1 || mode == 2) {
                int rr = m / T_, t = m % T_;
                int h = n / DH_, d = n & (DH_ - 1);
                int NN = (mode == 2) ? NA_ : NRG_;
                out[(((size_t)t * H_ + h) * NN + rr) * DH_ + d] = v;
            } else {
                out[(size_t)m * N + n] = v;
            }
        }
    }
}

// ---------------------------------------------------------------------------
// Attention: one block per (a, t*H+h). 256 threads.
// energy[r] = dot(Q[t,h,a,:], K[t,h,r,:]) * 0.5, masked; softmax over r; PV.
// ---------------------------------------------------------------------------
__global__ void attn_kernel(const float* __restrict__ Qp, const float* __restrict__ Kp,
                            const float* __restrict__ Vp,
                            const int* __restrict__ am, const int* __restrict__ pm,
                            const int* __restrict__ vmk,
                            float* __restrict__ Y1) {
    int a = blockIdx.x;
    int th = blockIdx.y;
    int t = th / H_, h = th % H_;
    int tid = threadIdx.x;

    __shared__ float qs[DH_];
    __shared__ float ps[NRG_];
    __shared__ float red[256];
    __shared__ float ys[4][DH_];

    const float* Qrow = Qp + (((size_t)t * H_ + h) * NA_ + a) * DH_;
    if (tid < DH_) qs[tid] = Qrow[tid];
    int valid = vmk[t * NA_ + a];
    __syncthreads();

    const float* Kbase = Kp + ((size_t)t * H_ + h) * NRG_ * DH_;
    const float* Vbase = Vp + ((size_t)t * H_ + h) * NRG_ * DH_;

    float mymax = -INFINITY;
#pragma unroll
    for (int rr = 0; rr < 4; ++rr) {
        int r = tid + rr * 256;
        float e;
        if (valid && am[((size_t)t * NA_ + a) * NRG_ + r] && pm[t * NRG_ + r]) {
            const float* Krow = Kbase + (size_t)r * DH_;
            float s = 0.0f;
#pragma unroll
            for (int d = 0; d < DH_; ++d) s += qs[d] * Krow[d];
            e = s * 0.5f;
        } else {
            e = NEGV;
        }
        ps[r] = e;
        mymax = fmaxf(mymax, e);
    }
    red[tid] = mymax;
    __syncthreads();
    for (int s = 128; s > 0; s >>= 1) {
        if (tid < s) red[tid] = fmaxf(red[tid], red[tid + s]);
        __syncthreads();
    }
    float mx = red[0];
    __syncthreads();

    float mysum = 0.0f;
#pragma unroll
    for (int rr = 0; rr < 4; ++rr) {
        int r = tid + rr * 256;
        float p = expf(ps[r] - mx);
        ps[r] = p;
        mysum += p;
    }
    red[tid] = mysum;
    __syncthreads();
    for (int s = 128; s > 0; s >>= 1) {
        if (tid < s) red[tid] += red[tid + s];
        __syncthreads();
    }
    float inv = 1.0f / red[0];

    int d = tid & 63, g = tid >> 6;
    float accv = 0.0f;
    for (int r = g * 256; r < (g + 1) * 256; ++r) {
        accv += ps[r] * Vbase[(size_t)r * DH_ + d];
    }
    ys[g][d] = accv;
    __syncthreads();
    if (tid < DH_) {
        float y = (ys[0][tid] + ys[1][tid] + ys[2][tid] + ys[3][tid]) * inv;
        Y1[((size_t)a * T_ + t) * D_ + h * DH_ + tid] = y;
    }
}

// ---------------------------------------------------------------------------
// Final LayerNorm: Z = ln(F2) row-wise, written to d_out.
// ---------------------------------------------------------------------------
__global__ void ln_apply(const float* __restrict__ X, const float* __restrict__ g,
                         const float* __restrict__ b, float* __restrict__ out) {
    int row = blockIdx.x;
    int tid = threadIdx.x;
    float x = X[(size_t)row * D_ + tid];
    __shared__ float red[256];
    red[tid] = x;
    __syncthreads();
    for (int s = 128; s > 0; s >>= 1) {
        if (tid < s) red[tid] += red[tid + s];
        __syncthreads();
    }
    float mean = red[0] * (1.0f / 256.0f);
    __syncthreads();
    float dx = x - mean;
    red[tid] = dx * dx;
    __syncthreads();
    for (int s = 128; s > 0; s >>= 1) {
        if (tid < s) red[tid] += red[tid + s];
        __syncthreads();
    }
    float rstd = rsqrtf(red[0] * (1.0f / 256.0f) + 1e-5f);
    out[(size_t)row * D_ + tid] = dx * rstd * g[tid] + b[tid];
}

// ---------------------------------------------------------------------------
extern "C" void kernel_launch(void* const* d_in, const int* in_sizes, int n_in,
                              void* d_out, int out_size, void* d_ws, size_t ws_size,
                              hipStream_t stream) {
    const float* agent   = (const float*)d_in[0];
    const float* rg      = (const float*)d_in[1];
    const float* ln_x_g  = (const float*)d_in[2];
    const float* ln_x_b  = (const float*)d_in[3];
    const float* wk      = (const float*)d_in[4];
    const float* bk      = (const float*)d_in[5];
    const float* wv      = (const float*)d_in[6];
    const float* bv      = (const float*)d_in[7];
    const float* wq      = (const float*)d_in[8];
    const float* bq      = (const float*)d_in[9];
    const float* q_scale = (const float*)d_in[10];
    const float* wy      = (const float*)d_in[11];
    const float* by      = (const float*)d_in[12];
    const float* wf1     = (const float*)d_in[13];
    const float* bf1     = (const float*)d_in[14];
    const float* wf2     = (const float*)d_in[15];
    const float* bf2     = (const float*)d_in[16];
    const float* ln_z_g  = (const float*)d_in[17];
    const float* ln_z_b  = (const float*)d_in[18];
    const int*   am      = (const int*)d_in[19];
    const int*   pm      = (const int*)d_in[20];
    const int*   vmk     = (const int*)d_in[21];

    float* Z  = (float*)d_out;                       // NA*T*D
    float* Qp = Z + (size_t)NA_ * T_ * D_;           // T*H*NA*DH
    float* Kp = Qp + (size_t)NA_ * T_ * D_;          // T*H*NRG*DH
    float* Vp = Kp + (size_t)NRG_ * T_ * D_;

    float* mu = (float*)d_ws;                        // (NA+NRG)*T  (agent rows, then rg rows)
    float* rs = mu + (size_t)(NA_ + NRG_) * T_;
    float* Y1 = rs + (size_t)(NA_ + NRG_) * T_;      // NA*T*D
    float* S  = Y1 + (size_t)NA_ * T_ * D_;          // NA*T*D
    float* F1 = S + (size_t)NA_ * T_ * D_;           // NA*T*KEXP*D
    float* F2 = F1 + (size_t)NA_ * T_ * D_ * KEXP_;  // NA*T*D
    float* mu_a = mu;
    float* rs_a = rs;
    float* mu_r = mu + (size_t)NA_ * T_;
    float* rs_r = rs + (size_t)NA_ * T_;

    dim3 blk(256);

    // 1. LayerNorm stats for all agent+rg rows
    ln_stats<<<dim3((NA_ + NRG_) * T_), blk, 0, stream>>>(agent, rg, mu, rs);

    // 2. K = relu(ln(rg) @ wk + bk) -> Kp (t,h,r,d)
    gemm_fused<<<dim3(NRG_ * T_ / BM, 256 / BN), blk, 0, stream>>>(
        rg, wk, bk, mu_r, rs_r, ln_x_g, ln_x_b, nullptr, nullptr, Kp,
        NRG_ * T_, 256, 256, 1, 1);

    // 3. V = relu(ln(rg) @ wv + bv) -> Vp
    gemm_fused<<<dim3(NRG_ * T_ / BM, 256 / BN), blk, 0, stream>>>(
        rg, wv, bv, mu_r, rs_r, ln_x_g, ln_x_b, nullptr, nullptr, Vp,
        NRG_ * T_, 256, 256, 1, 1);

    // 4. Q = relu(ln(agent) @ wq + bq) * q_scale -> Qp
    gemm_fused<<<dim3(NA_ * T_ / BM, 256 / BN), blk, 0, stream>>>(
        agent, wq, bq, mu_a, rs_a, ln_x_g, ln_x_b, q_scale, nullptr, Qp,
        NA_ * T_, 256, 256, 2, 1);

    // 5. Attention -> Y1 (a,t,d)
    attn_kernel<<<dim3(NA_, T_ * H_), blk, 0, stream>>>(Qp, Kp, Vp, am, pm, vmk, Y1);

    // 6. S = relu(Y1 @ wy + by) + ln(agent)
    gemm_fused<<<dim3(NA_ * T_ / BM, 256 / BN), blk, 0, stream>>>(
        Y1, wy, by, mu_a, rs_a, ln_x_g, ln_x_b, nullptr, agent, S,
        NA_ * T_, 256, 256, 3, 0);

    // 7. F1 = relu(S @ wf1 + bf1)
    gemm_fused<<<dim3(NA_ * T_ / BM, 1024 / BN), blk, 0, stream>>>(
        S, wf1, bf1, nullptr, nullptr, nullptr, nullptr, nullptr, nullptr, F1,
        NA_ * T_, 1024, 256, 0, 0);

    // 8. F2 = relu(F1 @ wf2 + bf2)
    gemm_fused<<<dim3(NA_ * T_ / BM, 256 / BN), blk, 0, stream>>>(
        F1, wf2, bf2, nullptr, nullptr, nullptr, nullptr, nullptr, nullptr, F2,
        NA_ * T_, 256, 1024, 0, 0);

    // 9. Z = ln(F2)
    ln_apply<<<dim3(NA_ * T_), blk, 0, stream>>>(F2, ln_z_g, ln_z_b, Z);
}

// Round 2
// 550.151 us; speedup vs baseline: 3.5120x; 3.5120x over previous
//
#include <hip/hip_runtime.h>

#define T_   91
#define D_   256
#define H_   4
#define DH_  64
#define NA_  128
#define NRG_ 1024
#define KEXP_ 4

static constexpr float NEGV = -1e10f;

typedef float f32x4 __attribute__((ext_vector_type(4)));
typedef short bf16x8 __attribute__((ext_vector_type(8)));

__device__ inline ushort f2bf(float f) {
    union { float f; unsigned u; } v; v.f = f;
    unsigned r = (v.u + 0x7fffu + ((v.u >> 16) & 1u)) >> 16;
    return (ushort)r;
}
__device__ inline unsigned pk2(float a, float b) {
    return (unsigned)f2bf(a) | ((unsigned)f2bf(b) << 16);
}
__device__ inline float bf2f(ushort b) {
    union { unsigned u; float f; } v; v.u = ((unsigned)b) << 16;
    return v.f;
}

// ---------------------------------------------------------------------------
// LN stats: rows [0, NA*T) = agent, [NA*T, ...) = rg
// ---------------------------------------------------------------------------
__global__ void ln_stats(const float* __restrict__ agent, const float* __restrict__ rg,
                         float* __restrict__ mu, float* __restrict__ rs) {
    int row = blockIdx.x;
    int tid = threadIdx.x;
    const float* src = (row < NA_ * T_) ? (agent + (size_t)row * D_)
                                        : (rg + (size_t)(row - NA_ * T_) * D_);
    float x = src[tid];
    __shared__ float red[256];
    red[tid] = x;
    __syncthreads();
    for (int s = 128; s > 0; s >>= 1) {
        if (tid < s) red[tid] += red[tid + s];
        __syncthreads();
    }
    float mean = red[0] * (1.0f / 256.0f);
    __syncthreads();
    float dx = x - mean;
    red[tid] = dx * dx;
    __syncthreads();
    for (int s = 128; s > 0; s >>= 1) {
        if (tid < s) red[tid] += red[tid + s];
        __syncthreads();
    }
    if (tid == 0) {
        mu[row] = mean;
        rs[row] = rsqrtf(red[0] * (1.0f / 256.0f) + 1e-5f);
    }
}

// ---------------------------------------------------------------------------
// Weight transpose + bf16 convert: dst[n][k] = bf16(W[k][n]);  dst is N x K
// ---------------------------------------------------------------------------
__global__ void prep_w(const float* __restrict__ W, ushort* __restrict__ dst,
                       int K, int N) {
    int idx = blockIdx.x * 256 + threadIdx.x;
    int n = idx / K, k = idx % K;
    dst[idx] = f2bf(W[(size_t)k * N + n]);
}

// ---------------------------------------------------------------------------
// Combined mask bit-pack: cm[(t*NA+a)*32 + w] bits r&31 of word r>>5
// One wave per (t,a); 16 ballots of 64 lanes.
// ---------------------------------------------------------------------------
__global__ void pack_mask(const int* __restrict__ am, const int* __restrict__ pm,
                          const int* __restrict__ vmk, unsigned* __restrict__ cm) {
    int idx = blockIdx.x * 4 + (threadIdx.x >> 6);
    int lane = threadIdx.x & 63;
    int t = idx / NA_, a = idx % NA_;
    int valid = vmk[t * NA_ + a];
    const int* amrow = am + (size_t)(t * NA_ + a) * NRG_;
    const int* pmrow = pm + (size_t)t * NRG_;
#pragma unroll
    for (int c = 0; c < 16; ++c) {
        int r = c * 64 + lane;
        bool bit = valid && amrow[r] && pmrow[r];
        unsigned long long msk = __ballot(bit);
        if (lane == 0) {
            cm[(size_t)idx * 32 + c * 2]     = (unsigned)msk;
            cm[(size_t)idx * 32 + c * 2 + 1] = (unsigned)(msk >> 32);
        }
    }
}

// ---------------------------------------------------------------------------
// bf16 MFMA GEMM: out = epilogue(A @ Bt^T + bias); Bt is N x K bf16.
// If Af != nullptr: A is fp32 with fused LayerNorm (mu/rs/lng/lnb), else Ab bf16.
// mode 0: relu -> outb bf16 row-major            (F1)
// mode 1: relu -> outf fp32 (t,h,r,d), NN=NRG    (K, V)
// mode 2: relu*qscale -> outf fp32 (t,h,a,d) NA  (Q)
// mode 3: relu + ln(resid) -> outb bf16          (S = Y2 + agent_n)
// mode 4: relu -> outf fp32 row-major            (F2)
// ---------------------------------------------------------------------------
__global__ __launch_bounds__(256) void gemm_bf16(
    const float* __restrict__ Af, const ushort* __restrict__ Ab,
    const ushort* __restrict__ Bt, const float* __restrict__ bias,
    const float* __restrict__ mu, const float* __restrict__ rsg,
    const float* __restrict__ lng, const float* __restrict__ lnb,
    const float* __restrict__ qscale, const float* __restrict__ resid,
    float* __restrict__ outf, ushort* __restrict__ outb,
    int M, int N, int K, int mode) {
    __shared__ ushort As[64][72];
    __shared__ ushort Bs[64][72];
    int bm = blockIdx.x * 64, bn = blockIdx.y * 64;
    int tid = threadIdx.x;
    int w = tid >> 6, lane = tid & 63;
    int wm = w >> 1, wn = w & 1;
    int l15 = lane & 15, l4 = lane >> 4;

    f32x4 acc[2][2];
#pragma unroll
    for (int i = 0; i < 2; ++i)
#pragma unroll
        for (int j = 0; j < 2; ++j)
#pragma unroll
            for (int r = 0; r < 4; ++r) acc[i][j][r] = 0.0f;

    for (int k0 = 0; k0 < K; k0 += 64) {
        if (Af) {
#pragma unroll
            for (int it = 0; it < 4; ++it) {
                int li = tid + it * 256;
                int row = li >> 4, c4 = (li & 15) * 4;
                int m = bm + row;
                f32x4 v = *(const f32x4*)(Af + (size_t)m * K + k0 + c4);
                float mm = mu[m], rr = rsg[m];
                float x0 = (v[0] - mm) * rr * lng[k0 + c4 + 0] + lnb[k0 + c4 + 0];
                float x1 = (v[1] - mm) * rr * lng[k0 + c4 + 1] + lnb[k0 + c4 + 1];
                float x2 = (v[2] - mm) * rr * lng[k0 + c4 + 2] + lnb[k0 + c4 + 2];
                float x3 = (v[3] - mm) * rr * lng[k0 + c4 + 3] + lnb[k0 + c4 + 3];
                *(uint2*)&As[row][c4] = make_uint2(pk2(x0, x1), pk2(x2, x3));
            }
        } else {
#pragma unroll
            for (int it = 0; it < 2; ++it) {
                int li = tid + it * 256;
                int row = li >> 3, c8 = (li & 7) * 8;
                *(bf16x8*)&As[row][c8] =
                    *(const bf16x8*)(Ab + (size_t)(bm + row) * K + k0 + c8);
            }
        }
#pragma unroll
        for (int it = 0; it < 2; ++it) {
            int li = tid + it * 256;
            int row = li >> 3, c8 = (li & 7) * 8;
            *(bf16x8*)&Bs[row][c8] =
                *(const bf16x8*)(Bt + (size_t)(bn + row) * K + k0 + c8);
        }
        __syncthreads();
#pragma unroll
        for (int kk = 0; kk < 2; ++kk) {
            bf16x8 af[2], bf[2];
#pragma unroll
            for (int i = 0; i < 2; ++i)
                af[i] = *(const bf16x8*)&As[wm * 32 + i * 16 + l15][kk * 32 + l4 * 8];
#pragma unroll
            for (int j = 0; j < 2; ++j)
                bf[j] = *(const bf16x8*)&Bs[wn * 32 + j * 16 + l15][kk * 32 + l4 * 8];
#pragma unroll
            for (int i = 0; i < 2; ++i)
#pragma unroll
                for (int j = 0; j < 2; ++j)
                    acc[i][j] = __builtin_amdgcn_mfma_f32_16x16x32_bf16(
                        af[i], bf[j], acc[i][j], 0, 0, 0);
        }
        __syncthreads();
    }

#pragma unroll
    for (int i = 0; i < 2; ++i)
#pragma unroll
        for (int j = 0; j < 2; ++j)
#pragma unroll
            for (int reg = 0; reg < 4; ++reg) {
                int m = bm + wm * 32 + i * 16 + l4 * 4 + reg;
                int n = bn + wn * 32 + j * 16 + l15;
                float v = acc[i][j][reg] + bias[n];
                v = fmaxf(v, 0.0f);
                if (mode == 2) v *= qscale[n & (DH_ - 1)];
                if (mode == 3) {
                    float a = resid[(size_t)m * D_ + n];
                    v += (a - mu[m]) * rsg[m] * lng[n] + lnb[n];
                }
                if (mode == 1 || mode == 2) {
                    int rr = m / T_, t = m % T_;
                    int h = n >> 6, d = n & (DH_ - 1);
                    int NN = (mode == 2) ? NA_ : NRG_;
                    outf[(((size_t)t * H_ + h) * NN + rr) * DH_ + d] = v;
                } else if (mode == 4) {
                    outf[(size_t)m * N + n] = v;
                } else {
                    outb[(size_t)m * N + n] = f2bf(v);
                }
            }
}

// ---------------------------------------------------------------------------
// V transpose: Vp fp32 (t,h,r,d) -> Vtb bf16 (t,h,d,r)
// ---------------------------------------------------------------------------
__global__ __launch_bounds__(256) void transpose_v(const float* __restrict__ Vp,
                                                   ushort* __restrict__ Vtb) {
    int th = blockIdx.x;
    int rb = blockIdx.y * 64;
    int tid = threadIdx.x;
    __shared__ ushort tr[64][72];
#pragma unroll
    for (int it = 0; it < 4; ++it) {
        int li = tid + it * 256;
        int row = li >> 4, c4 = (li & 15) * 4;
        f32x4 v = *(const f32x4*)(Vp + ((size_t)th * NRG_ + rb + row) * DH_ + c4);
        *(uint2*)&tr[row][c4] = make_uint2(pk2(v[0], v[1]), pk2(v[2], v[3]));
    }
    __syncthreads();
#pragma unroll
    for (int it = 0; it < 2; ++it) {
        int li = tid + it * 256;
        int dh = li >> 3, r8 = (li & 7) * 8;
        bf16x8 g;
#pragma unroll
        for (int j = 0; j < 8; ++j) g[j] = (short)tr[r8 + j][dh];
        *(bf16x8*)(Vtb + ((size_t)th * DH_ + dh) * NRG_ + rb + r8) = g;
    }
}

// ---------------------------------------------------------------------------
// Flash attention: block = (t*H+h, a-half). 4 waves, each owns 16 a-rows.
// ---------------------------------------------------------------------------
__global__ __launch_bounds__(256) void attn_flash(
    const float* __restrict__ Qp, const float* __restrict__ Kp,
    const ushort* __restrict__ Vtb, const unsigned* __restrict__ cm,
    ushort* __restrict__ Y1b) {
    int bx = blockIdx.x;
    int t = bx >> 2, h = bx & 3;
    int ah = blockIdx.y;
    int tid = threadIdx.x;
    int w = tid >> 6, lane = tid & 63;
    int l15 = lane & 15, l4 = lane >> 4;

    __shared__ ushort Qs[64][72];
    __shared__ ushort Ks[128][72];
    __shared__ ushort Vts[64][136];
    __shared__ ushort Ps[64][136];
    __shared__ unsigned cmw[64][4];

    const float* Qbase = Qp + ((size_t)bx * NA_ + ah * 64) * DH_;
#pragma unroll
    for (int it = 0; it < 4; ++it) {
        int li = tid + it * 256;
        int row = li >> 4, c4 = (li & 15) * 4;
        f32x4 v = *(const f32x4*)(Qbase + row * DH_ + c4);
        *(uint2*)&Qs[row][c4] = make_uint2(pk2(v[0], v[1]), pk2(v[2], v[3]));
    }
    __syncthreads();
    bf16x8 qf[2];
#pragma unroll
    for (int kk = 0; kk < 2; ++kk)
        qf[kk] = *(const bf16x8*)&Qs[w * 16 + l15][kk * 32 + l4 * 8];

    f32x4 o[4];
    float mrun[4], lrun[4];
#pragma unroll
    for (int ds = 0; ds < 4; ++ds)
#pragma unroll
        for (int r = 0; r < 4; ++r) o[ds][r] = 0.0f;
#pragma unroll
    for (int r = 0; r < 4; ++r) { mrun[r] = -INFINITY; lrun[r] = 0.0f; }

    for (int rt = 0; rt < 8; ++rt) {
        int r0 = rt * 128;
        // stage K (fp32 -> bf16)
#pragma unroll
        for (int it = 0; it < 8; ++it) {
            int li = tid + it * 256;
            int row = li >> 4, c4 = (li & 15) * 4;
            f32x4 v = *(const f32x4*)(Kp + ((size_t)bx * NRG_ + r0 + row) * DH_ + c4);
            *(uint2*)&Ks[row][c4] = make_uint2(pk2(v[0], v[1]), pk2(v[2], v[3]));
        }
        // stage V^T (bf16 direct)
#pragma unroll
        for (int it = 0; it < 4; ++it) {
            int li = tid + it * 256;
            int dh = li >> 4, r8 = (li & 15) * 8;
            *(bf16x8*)&Vts[dh][r8] =
                *(const bf16x8*)(Vtb + ((size_t)bx * DH_ + dh) * NRG_ + r0 + r8);
        }
        // stage mask words
        {
            int a = tid >> 2, wd = tid & 3;
            cmw[a][wd] = cm[((size_t)t * NA_ + ah * 64 + a) * 32 + rt * 4 + wd];
        }
        __syncthreads();

        // E = Q @ K^T
        f32x4 e[8];
#pragma unroll
        for (int rs = 0; rs < 8; ++rs) {
#pragma unroll
            for (int r = 0; r < 4; ++r) e[rs][r] = 0.0f;
#pragma unroll
            for (int kk = 0; kk < 2; ++kk) {
                bf16x8 kf = *(const bf16x8*)&Ks[rs * 16 + l15][kk * 32 + l4 * 8];
                e[rs] = __builtin_amdgcn_mfma_f32_16x16x32_bf16(qf[kk], kf, e[rs], 0, 0, 0);
            }
        }

        // mask + online softmax
        float pmax[4] = {-INFINITY, -INFINITY, -INFINITY, -INFINITY};
#pragma unroll
        for (int rs = 0; rs < 8; ++rs)
#pragma unroll
            for (int reg = 0; reg < 4; ++reg) {
                int a_loc = w * 16 + l4 * 4 + reg;
                unsigned wd = cmw[a_loc][rs >> 1];
                int bit = (wd >> ((rs & 1) * 16 + l15)) & 1;
                float ev = bit ? e[rs][reg] * 0.5f : NEGV;
                e[rs][reg] = ev;
                pmax[reg] = fmaxf(pmax[reg], ev);
            }
#pragma unroll
        for (int off = 1; off < 16; off <<= 1)
#pragma unroll
            for (int reg = 0; reg < 4; ++reg)
                pmax[reg] = fmaxf(pmax[reg], __shfl_xor(pmax[reg], off));

        float sc[4], rsum[4];
#pragma unroll
        for (int reg = 0; reg < 4; ++reg) {
            float mnew = fmaxf(mrun[reg], pmax[reg]);
            sc[reg] = __expf(mrun[reg] - mnew);
            mrun[reg] = mnew;
            rsum[reg] = 0.0f;
        }
#pragma unroll
        for (int rs = 0; rs < 8; ++rs)
#pragma unroll
            for (int reg = 0; reg < 4; ++reg) {
                int a_loc = w * 16 + l4 * 4 + reg;
                float p = __expf(e[rs][reg] - mrun[reg]);
                Ps[a_loc][rs * 16 + l15] = f2bf(p);
                rsum[reg] += p;
            }
#pragma unroll
        for (int off = 1; off < 16; off <<= 1)
#pragma unroll
            for (int reg = 0; reg < 4; ++reg)
                rsum[reg] += __shfl_xor(rsum[reg], off);
#pragma unroll
        for (int reg = 0; reg < 4; ++reg)
            lrun[reg] = lrun[reg] * sc[reg] + rsum[reg];
#pragma unroll
        for (int ds = 0; ds < 4; ++ds)
#pragma unroll
            for (int reg = 0; reg < 4; ++reg) o[ds][reg] *= sc[reg];

        // PV: O += P @ V
#pragma unroll
        for (int rc = 0; rc < 4; ++rc) {
            bf16x8 pa = *(const bf16x8*)&Ps[w * 16 + l15][rc * 32 + l4 * 8];
#pragma unroll
            for (int ds = 0; ds < 4; ++ds) {
                bf16x8 vf = *(const bf16x8*)&Vts[ds * 16 + l15][rc * 32 + l4 * 8];
                o[ds] = __builtin_amdgcn_mfma_f32_16x16x32_bf16(pa, vf, o[ds], 0, 0, 0);
            }
        }
        __syncthreads();
    }

#pragma unroll
    for (int ds = 0; ds < 4; ++ds)
#pragma unroll
        for (int reg = 0; reg < 4; ++reg) {
            int a_g = ah * 64 + w * 16 + l4 * 4 + reg;
            int d = ds * 16 + l15;
            float y = o[ds][reg] / lrun[reg];
            Y1b[((size_t)a_g * T_ + t) * D_ + h * DH_ + d] = f2bf(y);
        }
}

// ---------------------------------------------------------------------------
// Final LayerNorm: Z = ln(F2)
// ---------------------------------------------------------------------------
__global__ void ln_apply(const float* __restrict__ X, const float* __restrict__ g,
                         const float* __restrict__ b, float* __restrict__ out) {
    int row = blockIdx.x;
    int tid = threadIdx.x;
    float x = X[(size_t)row * D_ + tid];
    __shared__ float red[256];
    red[tid] = x;
    __syncthreads();
    for (int s = 128; s > 0; s >>= 1) {
        if (tid < s) red[tid] += red[tid + s];
        __syncthreads();
    }
    float mean = red[0] * (1.0f / 256.0f);
    __syncthreads();
    float dx = x - mean;
    red[tid] = dx * dx;
    __syncthreads();
    for (int s = 128; s > 0; s >>= 1) {
        if (tid < s) red[tid] += red[tid + s];
        __syncthreads();
    }
    float rstd = rsqrtf(red[0] * (1.0f / 256.0f) + 1e-5f);
    out[(size_t)row * D_ + tid] = dx * rstd * g[tid] + b[tid];
}

// ---------------------------------------------------------------------------
extern "C" void kernel_launch(void* const* d_in, const int* in_sizes, int n_in,
                              void* d_out, int out_size, void* d_ws, size_t ws_size,
                              hipStream_t stream) {
    const float* agent   = (const float*)d_in[0];
    const float* rg      = (const float*)d_in[1];
    const float* ln_x_g  = (const float*)d_in[2];
    const float* ln_x_b  = (const float*)d_in[3];
    const float* wk      = (const float*)d_in[4];
    const float* bk      = (const float*)d_in[5];
    const float* wv      = (const float*)d_in[6];
    const float* bv      = (const float*)d_in[7];
    const float* wq      = (const float*)d_in[8];
    const float* bq      = (const float*)d_in[9];
    const float* q_scale = (const float*)d_in[10];
    const float* wy      = (const float*)d_in[11];
    const float* by      = (const float*)d_in[12];
    const float* wf1     = (const float*)d_in[13];
    const float* bf1     = (const float*)d_in[14];
    const float* wf2     = (const float*)d_in[15];
    const float* bf2     = (const float*)d_in[16];
    const float* ln_z_g  = (const float*)d_in[17];
    const float* ln_z_b  = (const float*)d_in[18];
    const int*   am      = (const int*)d_in[19];
    const int*   pm      = (const int*)d_in[20];
    const int*   vmk     = (const int*)d_in[21];

    float* Z  = (float*)d_out;
    float* Qp = Z + (size_t)NA_ * T_ * D_;
    float* Kp = Qp + (size_t)NA_ * T_ * D_;
    float* Vp = Kp + (size_t)NRG_ * T_ * D_;

    char* p = (char*)d_ws;
    float* mu = (float*)p;          p += (size_t)(NA_ + NRG_) * T_ * 4;
    float* rs = (float*)p;          p += (size_t)(NA_ + NRG_) * T_ * 4;
    ushort* wkt  = (ushort*)p;      p += (size_t)D_ * D_ * 2;
    ushort* wvt  = (ushort*)p;      p += (size_t)D_ * D_ * 2;
    ushort* wqt  = (ushort*)p;      p += (size_t)D_ * D_ * 2;
    ushort* wyt  = (ushort*)p;      p += (size_t)D_ * D_ * 2;
    ushort* wf1t = (ushort*)p;      p += (size_t)D_ * D_ * KEXP_ * 2;
    ushort* wf2t = (ushort*)p;      p += (size_t)D_ * D_ * KEXP_ * 2;
    unsigned* cm = (unsigned*)p;    p += (size_t)T_ * NA_ * 32 * 4;
    ushort* Vtb  = (ushort*)p;      p += (size_t)T_ * H_ * DH_ * NRG_ * 2;
    ushort* Y1b  = (ushort*)p;      p += (size_t)NA_ * T_ * D_ * 2;
    ushort* Sb   = (ushort*)p;      p += (size_t)NA_ * T_ * D_ * 2;
    ushort* F1b  = (ushort*)p;      p += (size_t)NA_ * T_ * D_ * KEXP_ * 2;
    float*  F2   = (float*)p;       p += (size_t)NA_ * T_ * D_ * 4;

    float* mu_a = mu;
    float* rs_a = rs;
    float* mu_r = mu + (size_t)NA_ * T_;
    float* rs_r = rs + (size_t)NA_ * T_;

    dim3 blk(256);

    ln_stats<<<dim3((NA_ + NRG_) * T_), blk, 0, stream>>>(agent, rg, mu, rs);

    prep_w<<<dim3(D_ * D_ / 256), blk, 0, stream>>>(wk, wkt, D_, D_);
    prep_w<<<dim3(D_ * D_ / 256), blk, 0, stream>>>(wv, wvt, D_, D_);
    prep_w<<<dim3(D_ * D_ / 256), blk, 0, stream>>>(wq, wqt, D_, D_);
    prep_w<<<dim3(D_ * D_ / 256), blk, 0, stream>>>(wy, wyt, D_, D_);
    prep_w<<<dim3(D_ * D_ * KEXP_ / 256), blk, 0, stream>>>(wf1, wf1t, D_, KEXP_ * D_);
    prep_w<<<dim3(D_ * D_ * KEXP_ / 256), blk, 0, stream>>>(wf2, wf2t, KEXP_ * D_, D_);

    pack_mask<<<dim3(T_ * NA_ / 4), blk, 0, stream>>>(am, pm, vmk, cm);

    // K = relu(ln(rg) @ wk + bk) -> Kp
    gemm_bf16<<<dim3(NRG_ * T_ / 64, 4), blk, 0, stream>>>(
        rg, nullptr, wkt, bk, mu_r, rs_r, ln_x_g, ln_x_b, nullptr, nullptr,
        Kp, nullptr, NRG_ * T_, D_, D_, 1);
    // V -> Vp
    gemm_bf16<<<dim3(NRG_ * T_ / 64, 4), blk, 0, stream>>>(
        rg, nullptr, wvt, bv, mu_r, rs_r, ln_x_g, ln_x_b, nullptr, nullptr,
        Vp, nullptr, NRG_ * T_, D_, D_, 1);
    // Q -> Qp
    gemm_bf16<<<dim3(NA_ * T_ / 64, 4), blk, 0, stream>>>(
        agent, nullptr, wqt, bq, mu_a, rs_a, ln_x_g, ln_x_b, q_scale, nullptr,
        Qp, nullptr, NA_ * T_, D_, D_, 2);

    transpose_v<<<dim3(T_ * H_, NRG_ / 64), blk, 0, stream>>>(Vp, Vtb);

    attn_flash<<<dim3(T_ * H_, 2), blk, 0, stream>>>(Qp, Kp, Vtb, cm, Y1b);

    // S = relu(Y1 @ wy + by) + ln(agent)
    gemm_bf16<<<dim3(NA_ * T_ / 64, 4), blk, 0, stream>>>(
        nullptr, Y1b, wyt, by, mu_a, rs_a, ln_x_g, ln_x_b, nullptr, agent,
        nullptr, Sb, NA_ * T_, D_, D_, 3);
    // F1 = relu(S @ wf1 + bf1)
    gemm_bf16<<<dim3(NA_ * T_ / 64, 16), blk, 0, stream>>>(
        nullptr, Sb, wf1t, bf1, nullptr, nullptr, nullptr, nullptr, nullptr, nullptr,
        nullptr, F1b, NA_ * T_, KEXP_ * D_, D_, 0);
    // F2 = relu(F1 @ wf2 + bf2)
    gemm_bf16<<<dim3(NA_ * T_ / 64, 4), blk, 0, stream>>>(
        nullptr, F1b, wf2t, bf2, nullptr, nullptr, nullptr, nullptr, nullptr, nullptr,
        F2, nullptr, NA_ * T_, D_, KEXP_ * D_, 4);

    ln_apply<<<dim3(NA_ * T_), blk, 0, stream>>>(F2, ln_z_g, ln_z_b, Z);
}

// Round 3
// 441.995 us; speedup vs baseline: 4.3714x; 1.2447x over previous
//
#include <hip/hip_runtime.h>

#define T_   91
#define D_   256
#define H_   4
#define DH_  64
#define NA_  128
#define NRG_ 1024
#define KEXP_ 4

typedef float f32x4 __attribute__((ext_vector_type(4)));
typedef short bf16x8 __attribute__((ext_vector_type(8)));

static constexpr float P_EPS = 1.3877787807814457e-17f;  // 2^-56, exact in bf16

__device__ inline ushort f2bf(float f) {
    union { float f; unsigned u; } v; v.f = f;
    unsigned r = (v.u + 0x7fffu + ((v.u >> 16) & 1u)) >> 16;
    return (ushort)r;
}
__device__ inline float bf2f(ushort b) {
    union { unsigned u; float f; } v; v.u = ((unsigned)b) << 16;
    return v.f;
}

// ---------------------------------------------------------------------------
// LayerNorm + bf16 convert, one block per row.
// rows [0, NA*T) = agent -> agn ; [NA*T, ...) = rg -> rgn
// ---------------------------------------------------------------------------
__global__ void ln_norm(const float* __restrict__ agent, const float* __restrict__ rg,
                        const float* __restrict__ g, const float* __restrict__ b,
                        ushort* __restrict__ agn, ushort* __restrict__ rgn) {
    int row = blockIdx.x;
    int tid = threadIdx.x;
    bool is_a = row < NA_ * T_;
    const float* src = is_a ? (agent + (size_t)row * D_)
                            : (rg + (size_t)(row - NA_ * T_) * D_);
    float x = src[tid];
    __shared__ float red[256];
    red[tid] = x;
    __syncthreads();
    for (int s = 128; s > 0; s >>= 1) {
        if (tid < s) red[tid] += red[tid + s];
        __syncthreads();
    }
    float mean = red[0] * (1.0f / 256.0f);
    __syncthreads();
    float dx = x - mean;
    red[tid] = dx * dx;
    __syncthreads();
    for (int s = 128; s > 0; s >>= 1) {
        if (tid < s) red[tid] += red[tid + s];
        __syncthreads();
    }
    float rstd = rsqrtf(red[0] * (1.0f / 256.0f) + 1e-5f);
    ushort* dst = is_a ? (agn + (size_t)row * D_)
                       : (rgn + (size_t)(row - NA_ * T_) * D_);
    dst[tid] = f2bf(dx * rstd * g[tid] + b[tid]);
}

// ---------------------------------------------------------------------------
// Weight transpose + bf16 convert: dst[n][k] = bf16(W[k][n])
// ---------------------------------------------------------------------------
__global__ void prep_w(const float* __restrict__ W, ushort* __restrict__ dst,
                       int K, int N) {
    int idx = blockIdx.x * 256 + threadIdx.x;
    int n = idx / K, k = idx % K;
    dst[idx] = f2bf(W[(size_t)k * N + n]);
}

// ---------------------------------------------------------------------------
// Mask bit-pack: cm[(t*NA+a)*32 + w], bit r&31 of word r>>5
// ---------------------------------------------------------------------------
__global__ void pack_mask(const int* __restrict__ am, const int* __restrict__ pm,
                          const int* __restrict__ vmk, unsigned* __restrict__ cm) {
    int idx = blockIdx.x * 4 + (threadIdx.x >> 6);
    int lane = threadIdx.x & 63;
    int t = idx / NA_, a = idx % NA_;
    int valid = vmk[t * NA_ + a];
    const int* amrow = am + (size_t)(t * NA_ + a) * NRG_;
    const int* pmrow = pm + (size_t)t * NRG_;
#pragma unroll
    for (int c = 0; c < 16; ++c) {
        int r = c * 64 + lane;
        bool bit = valid && amrow[r] && pmrow[r];
        unsigned long long msk = __ballot(bit);
        if (lane == 0) {
            cm[(size_t)idx * 32 + c * 2]     = (unsigned)msk;
            cm[(size_t)idx * 32 + c * 2 + 1] = (unsigned)(msk >> 32);
        }
    }
}

// ---------------------------------------------------------------------------
// bf16 MFMA GEMM, 64x64 tile, 4 waves. A: MxK bf16 row-major. Bt: NxK bf16.
// grid: (N/64, M/64)  -- N on x for A-tile L2 reuse.
// mode 1 (KV): n<256 -> out0/out2 (Kp f32 + Kb bf16, (t,h,r,d)); else out1/out3 (V)
// mode 2 (Q):  v*=qscale; out0 = Qp f32 (t,h,a,d); out2 = Qb bf16 (v*0.5)
// mode 3 (S):  v += bf16 resid; out2 bf16 row-major
// mode 0 (F1): out2 bf16 row-major
// mode 4 (F2): out0 f32 row-major
// ---------------------------------------------------------------------------
__global__ __launch_bounds__(256) void gemm_bf16(
    const ushort* __restrict__ Ab, const ushort* __restrict__ Bt,
    const float* __restrict__ bias0, const float* __restrict__ bias1,
    const float* __restrict__ qscale, const ushort* __restrict__ residb,
    float* __restrict__ out0, float* __restrict__ out1,
    ushort* __restrict__ out2, ushort* __restrict__ out3,
    int M, int N, int K, int mode) {
    __shared__ ushort As[64][72];
    __shared__ ushort Bs[64][72];
    int bn = blockIdx.x * 64, bm = blockIdx.y * 64;
    int tid = threadIdx.x;
    int w = tid >> 6, lane = tid & 63;
    int wm = w >> 1, wn = w & 1;
    int l15 = lane & 15, l4 = lane >> 4;

    f32x4 acc[2][2];
#pragma unroll
    for (int i = 0; i < 2; ++i)
#pragma unroll
        for (int j = 0; j < 2; ++j)
#pragma unroll
            for (int r = 0; r < 4; ++r) acc[i][j][r] = 0.0f;

    for (int k0 = 0; k0 < K; k0 += 64) {
#pragma unroll
        for (int it = 0; it < 2; ++it) {
            int li = tid + it * 256;
            int row = li >> 3, c8 = (li & 7) * 8;
            *(bf16x8*)&As[row][c8] =
                *(const bf16x8*)(Ab + (size_t)(bm + row) * K + k0 + c8);
            *(bf16x8*)&Bs[row][c8] =
                *(const bf16x8*)(Bt + (size_t)(bn + row) * K + k0 + c8);
        }
        __syncthreads();
#pragma unroll
        for (int kk = 0; kk < 2; ++kk) {
            bf16x8 af[2], bf[2];
#pragma unroll
            for (int i = 0; i < 2; ++i)
                af[i] = *(const bf16x8*)&As[wm * 32 + i * 16 + l15][kk * 32 + l4 * 8];
#pragma unroll
            for (int j = 0; j < 2; ++j)
                bf[j] = *(const bf16x8*)&Bs[wn * 32 + j * 16 + l15][kk * 32 + l4 * 8];
#pragma unroll
            for (int i = 0; i < 2; ++i)
#pragma unroll
                for (int j = 0; j < 2; ++j)
                    acc[i][j] = __builtin_amdgcn_mfma_f32_16x16x32_bf16(
                        af[i], bf[j], acc[i][j], 0, 0, 0);
        }
        __syncthreads();
    }

#pragma unroll
    for (int i = 0; i < 2; ++i)
#pragma unroll
        for (int j = 0; j < 2; ++j)
#pragma unroll
            for (int reg = 0; reg < 4; ++reg) {
                int m = bm + wm * 32 + i * 16 + l4 * 4 + reg;
                int n = bn + wn * 32 + j * 16 + l15;
                float bsv = (mode == 1) ? (n < 256 ? bias0[n] : bias1[n - 256])
                                        : bias0[n];
                float v = fmaxf(acc[i][j][reg] + bsv, 0.0f);
                if (mode == 1) {
                    int rr = m / T_, t = m % T_;
                    if (n < 256) {
                        int h = n >> 6, d = n & 63;
                        size_t idx = (((size_t)t * H_ + h) * NRG_ + rr) * DH_ + d;
                        out0[idx] = v;
                        out2[idx] = f2bf(v);
                    } else {
                        int n2 = n - 256;
                        int h = n2 >> 6, d = n2 & 63;
                        size_t idx = (((size_t)t * H_ + h) * NRG_ + rr) * DH_ + d;
                        out1[idx] = v;
                        out3[idx] = f2bf(v);
                    }
                } else if (mode == 2) {
                    v *= qscale[n & 63];
                    int a = m / T_, t = m % T_;
                    int h = n >> 6, d = n & 63;
                    size_t idx = (((size_t)t * H_ + h) * NA_ + a) * DH_ + d;
                    out0[idx] = v;
                    out2[idx] = f2bf(v * 0.5f);
                } else if (mode == 3) {
                    v += bf2f(residb[(size_t)m * D_ + n]);
                    out2[(size_t)m * N + n] = f2bf(v);
                } else if (mode == 4) {
                    out0[(size_t)m * N + n] = v;
                } else {
                    out2[(size_t)m * N + n] = f2bf(v);
                }
            }
}

// ---------------------------------------------------------------------------
// V transpose bf16: Vb (t,h,r,d) -> Vtb (t,h,d,r), XOR-swizzled LDS
// ---------------------------------------------------------------------------
__global__ __launch_bounds__(256) void transpose_v(const ushort* __restrict__ Vb,
                                                   ushort* __restrict__ Vtb) {
    int th = blockIdx.x;
    int rb = blockIdx.y * 64;
    int tid = threadIdx.x;
    __shared__ ushort tr[64][72];
#pragma unroll
    for (int it = 0; it < 2; ++it) {
        int li = tid + it * 256;
        int row = li >> 3, c8 = (li & 7) * 8;
        int swz = ((row >> 3) & 7) << 3;
        *(bf16x8*)&tr[row][c8 ^ swz] =
            *(const bf16x8*)(Vb + ((size_t)th * NRG_ + rb + row) * DH_ + c8);
    }
    __syncthreads();
#pragma unroll
    for (int it = 0; it < 2; ++it) {
        int li = tid + it * 256;
        int dh = li >> 3, r8 = (li & 7) * 8;
        int key = (tid & 7) << 3;  // = ((r8+j)>>3)<<3 for j<8
        bf16x8 g;
#pragma unroll
        for (int j = 0; j < 8; ++j) g[j] = (short)tr[r8 + j][dh ^ key];
        *(bf16x8*)(Vtb + ((size_t)th * DH_ + dh) * NRG_ + rb + r8) = g;
    }
}

// ---------------------------------------------------------------------------
// Flash attention v2: grid(2, T*H). 256 thr / 4 waves; wave owns 16 a-rows.
// No online max: Q,K >= 0 and tiny => e in [0, ~1]; masked -> P_EPS so
// fully-masked rows reproduce reference uniform softmax.
// ---------------------------------------------------------------------------
__global__ __launch_bounds__(256) void attn_flash(
    const ushort* __restrict__ Qb, const ushort* __restrict__ Kb,
    const ushort* __restrict__ Vtb, const unsigned* __restrict__ cm,
    ushort* __restrict__ Y1b) {
    int ah = blockIdx.x;
    int th = blockIdx.y;
    int t = th >> 2, h = th & 3;
    int tid = threadIdx.x;
    int w = tid >> 6, lane = tid & 63;
    int l15 = lane & 15, l4 = lane >> 4;

    __shared__ ushort Ks[64][72];
    __shared__ ushort Vts[64][72];
    __shared__ ushort Ps[64][72];
    __shared__ unsigned cmw[64][2];

    bf16x8 qf[2];
#pragma unroll
    for (int kk = 0; kk < 2; ++kk)
        qf[kk] = *(const bf16x8*)(Qb + ((size_t)th * NA_ + ah * 64 + w * 16 + l15) * DH_
                                  + kk * 32 + l4 * 8);

    f32x4 o[4];
    float rsum[4] = {0.0f, 0.0f, 0.0f, 0.0f};
#pragma unroll
    for (int ds = 0; ds < 4; ++ds)
#pragma unroll
        for (int r = 0; r < 4; ++r) o[ds][r] = 0.0f;

    for (int rt = 0; rt < 16; ++rt) {
        int r0 = rt * 64;
#pragma unroll
        for (int it = 0; it < 2; ++it) {
            int li = tid + it * 256;
            int row = li >> 3, c8 = (li & 7) * 8;
            *(bf16x8*)&Ks[row][c8] =
                *(const bf16x8*)(Kb + ((size_t)th * NRG_ + r0 + row) * DH_ + c8);
            *(bf16x8*)&Vts[row][c8] =
                *(const bf16x8*)(Vtb + ((size_t)th * DH_ + row) * NRG_ + r0 + c8);
        }
        if (tid < 128) {
            int a = tid >> 1, wd = tid & 1;
            cmw[a][wd] = cm[((size_t)t * NA_ + ah * 64 + a) * 32 + rt * 2 + wd];
        }
        __syncthreads();

        // E = Q @ K^T (scale folded into Qb)
        f32x4 e[4];
#pragma unroll
        for (int rs = 0; rs < 4; ++rs) {
#pragma unroll
            for (int r = 0; r < 4; ++r) e[rs][r] = 0.0f;
#pragma unroll
            for (int kk = 0; kk < 2; ++kk) {
                bf16x8 kf = *(const bf16x8*)&Ks[rs * 16 + l15][kk * 32 + l4 * 8];
                e[rs] = __builtin_amdgcn_mfma_f32_16x16x32_bf16(qf[kk], kf, e[rs], 0, 0, 0);
            }
        }

        // mask -> p = exp(e) or eps; accumulate row-sums; stash bf16 P
#pragma unroll
        for (int reg = 0; reg < 4; ++reg) {
            int a_loc = w * 16 + l4 * 4 + reg;
            unsigned w0 = cmw[a_loc][0], w1 = cmw[a_loc][1];
#pragma unroll
            for (int rs = 0; rs < 4; ++rs) {
                unsigned wd = (rs & 2) ? w1 : w0;
                int bit = (wd >> ((rs & 1) * 16 + l15)) & 1;
                float p = bit ? __expf(e[rs][reg]) : P_EPS;
                rsum[reg] += p;
                Ps[a_loc][rs * 16 + l15] = f2bf(p);
            }
        }

        // O += P @ V
#pragma unroll
        for (int rc = 0; rc < 2; ++rc) {
            bf16x8 pa = *(const bf16x8*)&Ps[w * 16 + l15][rc * 32 + l4 * 8];
#pragma unroll
            for (int ds = 0; ds < 4; ++ds) {
                bf16x8 vf = *(const bf16x8*)&Vts[ds * 16 + l15][rc * 32 + l4 * 8];
                o[ds] = __builtin_amdgcn_mfma_f32_16x16x32_bf16(pa, vf, o[ds], 0, 0, 0);
            }
        }
        __syncthreads();
    }

#pragma unroll
    for (int off = 1; off < 16; off <<= 1)
#pragma unroll
        for (int reg = 0; reg < 4; ++reg)
            rsum[reg] += __shfl_xor(rsum[reg], off);
    float rinv[4];
#pragma unroll
    for (int reg = 0; reg < 4; ++reg) rinv[reg] = 1.0f / rsum[reg];

#pragma unroll
    for (int ds = 0; ds < 4; ++ds)
#pragma unroll
        for (int reg = 0; reg < 4; ++reg) {
            int a_g = ah * 64 + w * 16 + l4 * 4 + reg;
            int d = ds * 16 + l15;
            Y1b[((size_t)a_g * T_ + t) * D_ + h * DH_ + d] = f2bf(o[ds][reg] * rinv[reg]);
        }
}

// ---------------------------------------------------------------------------
// Final LayerNorm: Z = ln(F2)
// ---------------------------------------------------------------------------
__global__ void ln_apply(const float* __restrict__ X, const float* __restrict__ g,
                         const float* __restrict__ b, float* __restrict__ out) {
    int row = blockIdx.x;
    int tid = threadIdx.x;
    float x = X[(size_t)row * D_ + tid];
    __shared__ float red[256];
    red[tid] = x;
    __syncthreads();
    for (int s = 128; s > 0; s >>= 1) {
        if (tid < s) red[tid] += red[tid + s];
        __syncthreads();
    }
    float mean = red[0] * (1.0f / 256.0f);
    __syncthreads();
    float dx = x - mean;
    red[tid] = dx * dx;
    __syncthreads();
    for (int s = 128; s > 0; s >>= 1) {
        if (tid < s) red[tid] += red[tid + s];
        __syncthreads();
    }
    float rstd = rsqrtf(red[0] * (1.0f / 256.0f) + 1e-5f);
    out[(size_t)row * D_ + tid] = dx * rstd * g[tid] + b[tid];
}

// ---------------------------------------------------------------------------
extern "C" void kernel_launch(void* const* d_in, const int* in_sizes, int n_in,
                              void* d_out, int out_size, void* d_ws, size_t ws_size,
                              hipStream_t stream) {
    const float* agent   = (const float*)d_in[0];
    const float* rg      = (const float*)d_in[1];
    const float* ln_x_g  = (const float*)d_in[2];
    const float* ln_x_b  = (const float*)d_in[3];
    const float* wk      = (const float*)d_in[4];
    const float* bk      = (const float*)d_in[5];
    const float* wv      = (const float*)d_in[6];
    const float* bv      = (const float*)d_in[7];
    const float* wq      = (const float*)d_in[8];
    const float* bq      = (const float*)d_in[9];
    const float* q_scale = (const float*)d_in[10];
    const float* wy      = (const float*)d_in[11];
    const float* by      = (const float*)d_in[12];
    const float* wf1     = (const float*)d_in[13];
    const float* bf1     = (const float*)d_in[14];
    const float* wf2     = (const float*)d_in[15];
    const float* bf2     = (const float*)d_in[16];
    const float* ln_z_g  = (const float*)d_in[17];
    const float* ln_z_b  = (const float*)d_in[18];
    const int*   am      = (const int*)d_in[19];
    const int*   pm      = (const int*)d_in[20];
    const int*   vmk     = (const int*)d_in[21];

    float* Z  = (float*)d_out;
    float* Qp = Z + (size_t)NA_ * T_ * D_;
    float* Kp = Qp + (size_t)NA_ * T_ * D_;
    float* Vp = Kp + (size_t)NRG_ * T_ * D_;

    char* p = (char*)d_ws;
    ushort* rgn_b = (ushort*)p;   p += (size_t)NRG_ * T_ * D_ * 2;   // also Vtb later
    ushort* agn_b = (ushort*)p;   p += (size_t)NA_ * T_ * D_ * 2;
    ushort* wkvt  = (ushort*)p;   p += (size_t)512 * 256 * 2;
    ushort* wqt   = (ushort*)p;   p += (size_t)256 * 256 * 2;
    ushort* wyt   = (ushort*)p;   p += (size_t)256 * 256 * 2;
    ushort* wf1t  = (ushort*)p;   p += (size_t)1024 * 256 * 2;
    ushort* wf2t  = (ushort*)p;   p += (size_t)256 * 1024 * 2;
    unsigned* cm  = (unsigned*)p; p += (size_t)T_ * NA_ * 32 * 4;
    ushort* Kb    = (ushort*)p;   p += (size_t)T_ * H_ * NRG_ * DH_ * 2;
    ushort* Vb    = (ushort*)p;   p += (size_t)T_ * H_ * NRG_ * DH_ * 2;  // also F1b later
    ushort* Qb    = (ushort*)p;   p += (size_t)T_ * H_ * NA_ * DH_ * 2;
    ushort* Y1b   = (ushort*)p;   p += (size_t)NA_ * T_ * D_ * 2;
    ushort* Sb    = (ushort*)p;   p += (size_t)NA_ * T_ * D_ * 2;

    ushort* Vtb = rgn_b;          // alias: rgn dead after KV GEMM
    ushort* F1b = Vb;             // alias: Vb dead after transpose_v
    float*  F2  = (float*)Y1b;    // alias: Y1b+Sb dead after F1 GEMM (11.9 MB)

    dim3 blk(256);

    ln_norm<<<dim3((NA_ + NRG_) * T_), blk, 0, stream>>>(
        agent, rg, ln_x_g, ln_x_b, agn_b, rgn_b);

    prep_w<<<dim3(256), blk, 0, stream>>>(wk, wkvt, 256, 256);
    prep_w<<<dim3(256), blk, 0, stream>>>(wv, wkvt + 65536, 256, 256);
    prep_w<<<dim3(256), blk, 0, stream>>>(wq, wqt, 256, 256);
    prep_w<<<dim3(256), blk, 0, stream>>>(wy, wyt, 256, 256);
    prep_w<<<dim3(1024), blk, 0, stream>>>(wf1, wf1t, 256, 1024);
    prep_w<<<dim3(1024), blk, 0, stream>>>(wf2, wf2t, 1024, 256);

    pack_mask<<<dim3(T_ * NA_ / 4), blk, 0, stream>>>(am, pm, vmk, cm);

    // K|V fused: N=512
    gemm_bf16<<<dim3(8, NRG_ * T_ / 64), blk, 0, stream>>>(
        rgn_b, wkvt, bk, bv, nullptr, nullptr,
        Kp, Vp, Kb, Vb, NRG_ * T_, 512, 256, 1);

    // Q
    gemm_bf16<<<dim3(4, NA_ * T_ / 64), blk, 0, stream>>>(
        agn_b, wqt, bq, nullptr, q_scale, nullptr,
        Qp, nullptr, Qb, nullptr, NA_ * T_, 256, 256, 2);

    transpose_v<<<dim3(T_ * H_, NRG_ / 64), blk, 0, stream>>>(Vb, Vtb);

    attn_flash<<<dim3(2, T_ * H_), blk, 0, stream>>>(Qb, Kb, Vtb, cm, Y1b);

    // S = relu(Y1 @ wy + by) + agent_n
    gemm_bf16<<<dim3(4, NA_ * T_ / 64), blk, 0, stream>>>(
        Y1b, wyt, by, nullptr, nullptr, agn_b,
        nullptr, nullptr, Sb, nullptr, NA_ * T_, 256, 256, 3);

    // F1 = relu(S @ wf1 + bf1)
    gemm_bf16<<<dim3(16, NA_ * T_ / 64), blk, 0, stream>>>(
        Sb, wf1t, bf1, nullptr, nullptr, nullptr,
        nullptr, nullptr, F1b, nullptr, NA_ * T_, 1024, 256, 0);

    // F2 = relu(F1 @ wf2 + bf2)
    gemm_bf16<<<dim3(4, NA_ * T_ / 64), blk, 0, stream>>>(
        F1b, wf2t, bf2, nullptr, nullptr, nullptr,
        F2, nullptr, nullptr, nullptr, NA_ * T_, 256, 1024, 4);

    ln_apply<<<dim3(NA_ * T_), blk, 0, stream>>>(F2, ln_z_g, ln_z_b, Z);
}

// Round 4
// 341.579 us; speedup vs baseline: 5.6565x; 1.2940x over previous
//
#include <hip/hip_runtime.h>

#define T_   91
#define D_   256
#define H_   4
#define DH_  64
#define NA_  128
#define NRG_ 1024
#define KEXP_ 4

typedef float f32x4 __attribute__((ext_vector_type(4)));
typedef short bf16x8 __attribute__((ext_vector_type(8)));

static constexpr float P_EPS = 1.3877787807814457e-17f;  // 2^-56, exact in bf16

__device__ inline ushort f2bf(float f) {
    union { float f; unsigned u; } v; v.f = f;
    unsigned r = (v.u + 0x7fffu + ((v.u >> 16) & 1u)) >> 16;
    return (ushort)r;
}
__device__ inline unsigned pk2(float a, float b) {
    return (unsigned)f2bf(a) | ((unsigned)f2bf(b) << 16);
}
__device__ inline float bf2f(ushort b) {
    union { unsigned u; float f; } v; v.u = ((unsigned)b) << 16;
    return v.f;
}

// ---------------------------------------------------------------------------
// LayerNorm + bf16 convert: ONE WAVE per 256-elem row. f32x4 loads, shfl reduce.
// rows [0, NA*T) = agent -> agn ; rest = rg -> rgn. 4 waves/block.
// ---------------------------------------------------------------------------
__global__ __launch_bounds__(256) void ln_norm(
    const float* __restrict__ agent, const float* __restrict__ rg,
    const float* __restrict__ g, const float* __restrict__ b,
    ushort* __restrict__ agn, ushort* __restrict__ rgn) {
    int row = blockIdx.x * 4 + (threadIdx.x >> 6);
    int lane = threadIdx.x & 63;
    bool is_a = row < NA_ * T_;
    const float* src = is_a ? (agent + (size_t)row * D_)
                            : (rg + (size_t)(row - NA_ * T_) * D_);
    f32x4 x = *(const f32x4*)(src + lane * 4);
    float s1 = x[0] + x[1] + x[2] + x[3];
    float s2 = x[0] * x[0] + x[1] * x[1] + x[2] * x[2] + x[3] * x[3];
#pragma unroll
    for (int off = 1; off < 64; off <<= 1) {
        s1 += __shfl_xor(s1, off);
        s2 += __shfl_xor(s2, off);
    }
    float mean = s1 * (1.0f / 256.0f);
    float var = s2 * (1.0f / 256.0f) - mean * mean;
    float rstd = rsqrtf(var + 1e-5f);
    f32x4 gv = *(const f32x4*)(g + lane * 4);
    f32x4 bv = *(const f32x4*)(b + lane * 4);
    float y0 = (x[0] - mean) * rstd * gv[0] + bv[0];
    float y1 = (x[1] - mean) * rstd * gv[1] + bv[1];
    float y2 = (x[2] - mean) * rstd * gv[2] + bv[2];
    float y3 = (x[3] - mean) * rstd * gv[3] + bv[3];
    ushort* dst = is_a ? (agn + (size_t)row * D_)
                       : (rgn + (size_t)(row - NA_ * T_) * D_);
    *(uint2*)(dst + lane * 4) = make_uint2(pk2(y0, y1), pk2(y2, y3));
}

// ---------------------------------------------------------------------------
// Weight transpose + bf16 convert: dst[n][k] = bf16(W[k][n])
// ---------------------------------------------------------------------------
__global__ void prep_w(const float* __restrict__ W, ushort* __restrict__ dst,
                       int K, int N) {
    int idx = blockIdx.x * 256 + threadIdx.x;
    int n = idx / K, k = idx % K;
    dst[idx] = f2bf(W[(size_t)k * N + n]);
}

// ---------------------------------------------------------------------------
// Mask bit-pack: cm[(t*NA+a)*32 + w], bit r&31 of word r>>5.
// 4 waves/block share one t -> stage pm row in LDS.
// ---------------------------------------------------------------------------
__global__ __launch_bounds__(256) void pack_mask(
    const int* __restrict__ am, const int* __restrict__ pm,
    const int* __restrict__ vmk, unsigned* __restrict__ cm) {
    int base = blockIdx.x * 4;
    int t = base / NA_;
    int w = threadIdx.x >> 6, lane = threadIdx.x & 63;
    __shared__ int pmS[NRG_];
#pragma unroll
    for (int i = 0; i < 4; ++i) pmS[threadIdx.x + i * 256] = pm[(size_t)t * NRG_ + threadIdx.x + i * 256];
    __syncthreads();
    int idx = base + w;
    int a = idx & (NA_ - 1);
    int valid = vmk[t * NA_ + a];
    const int* amrow = am + (size_t)idx * NRG_;
#pragma unroll
    for (int c = 0; c < 16; ++c) {
        int r = c * 64 + lane;
        bool bit = valid && amrow[r] && pmS[r];
        unsigned long long msk = __ballot(bit);
        if (lane == 0) {
            cm[(size_t)idx * 32 + c * 2]     = (unsigned)msk;
            cm[(size_t)idx * 32 + c * 2 + 1] = (unsigned)(msk >> 32);
        }
    }
}

// ---------------------------------------------------------------------------
// bf16 MFMA GEMM, 64x64 tile, 4 waves. A: MxK bf16 row-major. Bt: NxK bf16.
// grid: (N/64, M/64)  -- N on x for A-tile L2 reuse.
// mode 1 (KV): n<256 -> out0/out2 (Kp f32 + Kb bf16, (t,h,r,d)); else out1/out3 (V)
// mode 2 (Q):  v*=qscale; out0 = Qp f32 (t,h,a,d); out2 = Qb bf16 (v*0.5)
// mode 3 (S):  v += bf16 resid; out2 bf16 row-major
// mode 0 (F1): out2 bf16 row-major
// mode 4 (F2): out0 f32 row-major
// ---------------------------------------------------------------------------
__global__ __launch_bounds__(256) void gemm_bf16(
    const ushort* __restrict__ Ab, const ushort* __restrict__ Bt,
    const float* __restrict__ bias0, const float* __restrict__ bias1,
    const float* __restrict__ qscale, const ushort* __restrict__ residb,
    float* __restrict__ out0, float* __restrict__ out1,
    ushort* __restrict__ out2, ushort* __restrict__ out3,
    int M, int N, int K, int mode) {
    __shared__ ushort As[64][72];
    __shared__ ushort Bs[64][72];
    int bn = blockIdx.x * 64, bm = blockIdx.y * 64;
    int tid = threadIdx.x;
    int w = tid >> 6, lane = tid & 63;
    int wm = w >> 1, wn = w & 1;
    int l15 = lane & 15, l4 = lane >> 4;

    f32x4 acc[2][2];
#pragma unroll
    for (int i = 0; i < 2; ++i)
#pragma unroll
        for (int j = 0; j < 2; ++j)
#pragma unroll
            for (int r = 0; r < 4; ++r) acc[i][j][r] = 0.0f;

    for (int k0 = 0; k0 < K; k0 += 64) {
#pragma unroll
        for (int it = 0; it < 2; ++it) {
            int li = tid + it * 256;
            int row = li >> 3, c8 = (li & 7) * 8;
            *(bf16x8*)&As[row][c8] =
                *(const bf16x8*)(Ab + (size_t)(bm + row) * K + k0 + c8);
            *(bf16x8*)&Bs[row][c8] =
                *(const bf16x8*)(Bt + (size_t)(bn + row) * K + k0 + c8);
        }
        __syncthreads();
#pragma unroll
        for (int kk = 0; kk < 2; ++kk) {
            bf16x8 af[2], bf[2];
#pragma unroll
            for (int i = 0; i < 2; ++i)
                af[i] = *(const bf16x8*)&As[wm * 32 + i * 16 + l15][kk * 32 + l4 * 8];
#pragma unroll
            for (int j = 0; j < 2; ++j)
                bf[j] = *(const bf16x8*)&Bs[wn * 32 + j * 16 + l15][kk * 32 + l4 * 8];
#pragma unroll
            for (int i = 0; i < 2; ++i)
#pragma unroll
                for (int j = 0; j < 2; ++j)
                    acc[i][j] = __builtin_amdgcn_mfma_f32_16x16x32_bf16(
                        af[i], bf[j], acc[i][j], 0, 0, 0);
        }
        __syncthreads();
    }

#pragma unroll
    for (int i = 0; i < 2; ++i)
#pragma unroll
        for (int j = 0; j < 2; ++j)
#pragma unroll
            for (int reg = 0; reg < 4; ++reg) {
                int m = bm + wm * 32 + i * 16 + l4 * 4 + reg;
                int n = bn + wn * 32 + j * 16 + l15;
                float bsv = (mode == 1) ? (n < 256 ? bias0[n] : bias1[n - 256])
                                        : bias0[n];
                float v = fmaxf(acc[i][j][reg] + bsv, 0.0f);
                if (mode == 1) {
                    int rr = m / T_, t = m % T_;
                    if (n < 256) {
                        int h = n >> 6, d = n & 63;
                        size_t idx = (((size_t)t * H_ + h) * NRG_ + rr) * DH_ + d;
                        out0[idx] = v;
                        out2[idx] = f2bf(v);
                    } else {
                        int n2 = n - 256;
                        int h = n2 >> 6, d = n2 & 63;
                        size_t idx = (((size_t)t * H_ + h) * NRG_ + rr) * DH_ + d;
                        out1[idx] = v;
                        out3[idx] = f2bf(v);
                    }
                } else if (mode == 2) {
                    v *= qscale[n & 63];
                    int a = m / T_, t = m % T_;
                    int h = n >> 6, d = n & 63;
                    size_t idx = (((size_t)t * H_ + h) * NA_ + a) * DH_ + d;
                    out0[idx] = v;
                    out2[idx] = f2bf(v * 0.5f);
                } else if (mode == 3) {
                    v += bf2f(residb[(size_t)m * D_ + n]);
                    out2[(size_t)m * N + n] = f2bf(v);
                } else if (mode == 4) {
                    out0[(size_t)m * N + n] = v;
                } else {
                    out2[(size_t)m * N + n] = f2bf(v);
                }
            }
}

// ---------------------------------------------------------------------------
// V transpose bf16: Vb (t,h,r,d) -> Vtb (t,h,d,r), XOR-swizzled LDS
// ---------------------------------------------------------------------------
__global__ __launch_bounds__(256) void transpose_v(const ushort* __restrict__ Vb,
                                                   ushort* __restrict__ Vtb) {
    int th = blockIdx.x;
    int rb = blockIdx.y * 64;
    int tid = threadIdx.x;
    __shared__ ushort tr[64][72];
#pragma unroll
    for (int it = 0; it < 2; ++it) {
        int li = tid + it * 256;
        int row = li >> 3, c8 = (li & 7) * 8;
        int swz = ((row >> 3) & 7) << 3;
        *(bf16x8*)&tr[row][c8 ^ swz] =
            *(const bf16x8*)(Vb + ((size_t)th * NRG_ + rb + row) * DH_ + c8);
    }
    __syncthreads();
#pragma unroll
    for (int it = 0; it < 2; ++it) {
        int li = tid + it * 256;
        int dh = li >> 3, r8 = (li & 7) * 8;
        int key = (tid & 7) << 3;
        bf16x8 g;
#pragma unroll
        for (int j = 0; j < 8; ++j) g[j] = (short)tr[r8 + j][dh ^ key];
        *(bf16x8*)(Vtb + ((size_t)th * DH_ + dh) * NRG_ + rb + r8) = g;
    }
}

// ---------------------------------------------------------------------------
// Flash attention v2: grid(2, T*H). 256 thr / 4 waves; wave owns 16 a-rows.
// No online max: Q,K >= 0 and tiny => e in [0, ~1]; masked -> P_EPS so
// fully-masked rows reproduce reference uniform softmax.
// ---------------------------------------------------------------------------
__global__ __launch_bounds__(256) void attn_flash(
    const ushort* __restrict__ Qb, const ushort* __restrict__ Kb,
    const ushort* __restrict__ Vtb, const unsigned* __restrict__ cm,
    ushort* __restrict__ Y1b) {
    int ah = blockIdx.x;
    int th = blockIdx.y;
    int t = th >> 2, h = th & 3;
    int tid = threadIdx.x;
    int w = tid >> 6, lane = tid & 63;
    int l15 = lane & 15, l4 = lane >> 4;

    __shared__ ushort Ks[64][72];
    __shared__ ushort Vts[64][72];
    __shared__ ushort Ps[64][72];
    __shared__ unsigned cmw[64][2];

    bf16x8 qf[2];
#pragma unroll
    for (int kk = 0; kk < 2; ++kk)
        qf[kk] = *(const bf16x8*)(Qb + ((size_t)th * NA_ + ah * 64 + w * 16 + l15) * DH_
                                  + kk * 32 + l4 * 8);

    f32x4 o[4];
    float rsum[4] = {0.0f, 0.0f, 0.0f, 0.0f};
#pragma unroll
    for (int ds = 0; ds < 4; ++ds)
#pragma unroll
        for (int r = 0; r < 4; ++r) o[ds][r] = 0.0f;

    for (int rt = 0; rt < 16; ++rt) {
        int r0 = rt * 64;
#pragma unroll
        for (int it = 0; it < 2; ++it) {
            int li = tid + it * 256;
            int row = li >> 3, c8 = (li & 7) * 8;
            *(bf16x8*)&Ks[row][c8] =
                *(const bf16x8*)(Kb + ((size_t)th * NRG_ + r0 + row) * DH_ + c8);
            *(bf16x8*)&Vts[row][c8] =
                *(const bf16x8*)(Vtb + ((size_t)th * DH_ + row) * NRG_ + r0 + c8);
        }
        if (tid < 128) {
            int a = tid >> 1, wd = tid & 1;
            cmw[a][wd] = cm[((size_t)t * NA_ + ah * 64 + a) * 32 + rt * 2 + wd];
        }
        __syncthreads();

        // E = Q @ K^T (scale folded into Qb)
        f32x4 e[4];
#pragma unroll
        for (int rs = 0; rs < 4; ++rs) {
#pragma unroll
            for (int r = 0; r < 4; ++r) e[rs][r] = 0.0f;
#pragma unroll
            for (int kk = 0; kk < 2; ++kk) {
                bf16x8 kf = *(const bf16x8*)&Ks[rs * 16 + l15][kk * 32 + l4 * 8];
                e[rs] = __builtin_amdgcn_mfma_f32_16x16x32_bf16(qf[kk], kf, e[rs], 0, 0, 0);
            }
        }

        // mask -> p = exp(e) or eps; accumulate row-sums; stash bf16 P
#pragma unroll
        for (int reg = 0; reg < 4; ++reg) {
            int a_loc = w * 16 + l4 * 4 + reg;
            unsigned w0 = cmw[a_loc][0], w1 = cmw[a_loc][1];
#pragma unroll
            for (int rs = 0; rs < 4; ++rs) {
                unsigned wd = (rs & 2) ? w1 : w0;
                int bit = (wd >> ((rs & 1) * 16 + l15)) & 1;
                float p = bit ? __expf(e[rs][reg]) : P_EPS;
                rsum[reg] += p;
                Ps[a_loc][rs * 16 + l15] = f2bf(p);
            }
        }

        // O += P @ V
#pragma unroll
        for (int rc = 0; rc < 2; ++rc) {
            bf16x8 pa = *(const bf16x8*)&Ps[w * 16 + l15][rc * 32 + l4 * 8];
#pragma unroll
            for (int ds = 0; ds < 4; ++ds) {
                bf16x8 vf = *(const bf16x8*)&Vts[ds * 16 + l15][rc * 32 + l4 * 8];
                o[ds] = __builtin_amdgcn_mfma_f32_16x16x32_bf16(pa, vf, o[ds], 0, 0, 0);
            }
        }
        __syncthreads();
    }

#pragma unroll
    for (int off = 1; off < 16; off <<= 1)
#pragma unroll
        for (int reg = 0; reg < 4; ++reg)
            rsum[reg] += __shfl_xor(rsum[reg], off);
    float rinv[4];
#pragma unroll
    for (int reg = 0; reg < 4; ++reg) rinv[reg] = 1.0f / rsum[reg];

#pragma unroll
    for (int ds = 0; ds < 4; ++ds)
#pragma unroll
        for (int reg = 0; reg < 4; ++reg) {
            int a_g = ah * 64 + w * 16 + l4 * 4 + reg;
            int d = ds * 16 + l15;
            Y1b[((size_t)a_g * T_ + t) * D_ + h * DH_ + d] = f2bf(o[ds][reg] * rinv[reg]);
        }
}

// ---------------------------------------------------------------------------
// Final LayerNorm: Z = ln(F2), ONE WAVE per row, vectorized.
// ---------------------------------------------------------------------------
__global__ __launch_bounds__(256) void ln_apply(
    const float* __restrict__ X, const float* __restrict__ g,
    const float* __restrict__ b, float* __restrict__ out) {
    int row = blockIdx.x * 4 + (threadIdx.x >> 6);
    int lane = threadIdx.x & 63;
    f32x4 x = *(const f32x4*)(X + (size_t)row * D_ + lane * 4);
    float s1 = x[0] + x[1] + x[2] + x[3];
    float s2 = x[0] * x[0] + x[1] * x[1] + x[2] * x[2] + x[3] * x[3];
#pragma unroll
    for (int off = 1; off < 64; off <<= 1) {
        s1 += __shfl_xor(s1, off);
        s2 += __shfl_xor(s2, off);
    }
    float mean = s1 * (1.0f / 256.0f);
    float var = s2 * (1.0f / 256.0f) - mean * mean;
    float rstd = rsqrtf(var + 1e-5f);
    f32x4 gv = *(const f32x4*)(g + lane * 4);
    f32x4 bv = *(const f32x4*)(b + lane * 4);
    f32x4 y;
    y[0] = (x[0] - mean) * rstd * gv[0] + bv[0];
    y[1] = (x[1] - mean) * rstd * gv[1] + bv[1];
    y[2] = (x[2] - mean) * rstd * gv[2] + bv[2];
    y[3] = (x[3] - mean) * rstd * gv[3] + bv[3];
    *(f32x4*)(out + (size_t)row * D_ + lane * 4) = y;
}

// ---------------------------------------------------------------------------
extern "C" void kernel_launch(void* const* d_in, const int* in_sizes, int n_in,
                              void* d_out, int out_size, void* d_ws, size_t ws_size,
                              hipStream_t stream) {
    const float* agent   = (const float*)d_in[0];
    const float* rg      = (const float*)d_in[1];
    const float* ln_x_g  = (const float*)d_in[2];
    const float* ln_x_b  = (const float*)d_in[3];
    const float* wk      = (const float*)d_in[4];
    const float* bk      = (const float*)d_in[5];
    const float* wv      = (const float*)d_in[6];
    const float* bv      = (const float*)d_in[7];
    const float* wq      = (const float*)d_in[8];
    const float* bq      = (const float*)d_in[9];
    const float* q_scale = (const float*)d_in[10];
    const float* wy      = (const float*)d_in[11];
    const float* by      = (const float*)d_in[12];
    const float* wf1     = (const float*)d_in[13];
    const float* bf1     = (const float*)d_in[14];
    const float* wf2     = (const float*)d_in[15];
    const float* bf2     = (const float*)d_in[16];
    const float* ln_z_g  = (const float*)d_in[17];
    const float* ln_z_b  = (const float*)d_in[18];
    const int*   am      = (const int*)d_in[19];
    const int*   pm      = (const int*)d_in[20];
    const int*   vmk     = (const int*)d_in[21];

    float* Z  = (float*)d_out;
    float* Qp = Z + (size_t)NA_ * T_ * D_;
    float* Kp = Qp + (size_t)NA_ * T_ * D_;
    float* Vp = Kp + (size_t)NRG_ * T_ * D_;

    char* p = (char*)d_ws;
    ushort* rgn_b = (ushort*)p;   p += (size_t)NRG_ * T_ * D_ * 2;   // also Vtb later
    ushort* agn_b = (ushort*)p;   p += (size_t)NA_ * T_ * D_ * 2;
    ushort* wkvt  = (ushort*)p;   p += (size_t)512 * 256 * 2;
    ushort* wqt   = (ushort*)p;   p += (size_t)256 * 256 * 2;
    ushort* wyt   = (ushort*)p;   p += (size_t)256 * 256 * 2;
    ushort* wf1t  = (ushort*)p;   p += (size_t)1024 * 256 * 2;
    ushort* wf2t  = (ushort*)p;   p += (size_t)256 * 1024 * 2;
    unsigned* cm  = (unsigned*)p; p += (size_t)T_ * NA_ * 32 * 4;
    ushort* Kb    = (ushort*)p;   p += (size_t)T_ * H_ * NRG_ * DH_ * 2;
    ushort* Vb    = (ushort*)p;   p += (size_t)T_ * H_ * NRG_ * DH_ * 2;  // also F1b later
    ushort* Qb    = (ushort*)p;   p += (size_t)T_ * H_ * NA_ * DH_ * 2;
    ushort* Y1b   = (ushort*)p;   p += (size_t)NA_ * T_ * D_ * 2;
    ushort* Sb    = (ushort*)p;   p += (size_t)NA_ * T_ * D_ * 2;

    ushort* Vtb = rgn_b;          // alias: rgn dead after KV GEMM
    ushort* F1b = Vb;             // alias: Vb dead after transpose_v
    float*  F2  = (float*)Y1b;    // alias: Y1b+Sb dead after F1 GEMM

    dim3 blk(256);

    ln_norm<<<dim3((NA_ + NRG_) * T_ / 4), blk, 0, stream>>>(
        agent, rg, ln_x_g, ln_x_b, agn_b, rgn_b);

    prep_w<<<dim3(256), blk, 0, stream>>>(wk, wkvt, 256, 256);
    prep_w<<<dim3(256), blk, 0, stream>>>(wv, wkvt + 65536, 256, 256);
    prep_w<<<dim3(256), blk, 0, stream>>>(wq, wqt, 256, 256);
    prep_w<<<dim3(256), blk, 0, stream>>>(wy, wyt, 256, 256);
    prep_w<<<dim3(1024), blk, 0, stream>>>(wf1, wf1t, 256, 1024);
    prep_w<<<dim3(1024), blk, 0, stream>>>(wf2, wf2t, 1024, 256);

    pack_mask<<<dim3(T_ * NA_ / 4), blk, 0, stream>>>(am, pm, vmk, cm);

    // K|V fused: N=512
    gemm_bf16<<<dim3(8, NRG_ * T_ / 64), blk, 0, stream>>>(
        rgn_b, wkvt, bk, bv, nullptr, nullptr,
        Kp, Vp, Kb, Vb, NRG_ * T_, 512, 256, 1);

    // Q
    gemm_bf16<<<dim3(4, NA_ * T_ / 64), blk, 0, stream>>>(
        agn_b, wqt, bq, nullptr, q_scale, nullptr,
        Qp, nullptr, Qb, nullptr, NA_ * T_, 256, 256, 2);

    transpose_v<<<dim3(T_ * H_, NRG_ / 64), blk, 0, stream>>>(Vb, Vtb);

    attn_flash<<<dim3(2, T_ * H_), blk, 0, stream>>>(Qb, Kb, Vtb, cm, Y1b);

    // S = relu(Y1 @ wy + by) + agent_n
    gemm_bf16<<<dim3(4, NA_ * T_ / 64), blk, 0, stream>>>(
        Y1b, wyt, by, nullptr, nullptr, agn_b,
        nullptr, nullptr, Sb, nullptr, NA_ * T_, 256, 256, 3);

    // F1 = relu(S @ wf1 + bf1)
    gemm_bf16<<<dim3(16, NA_ * T_ / 64), blk, 0, stream>>>(
        Sb, wf1t, bf1, nullptr, nullptr, nullptr,
        nullptr, nullptr, F1b, nullptr, NA_ * T_, 1024, 256, 0);

    // F2 = relu(F1 @ wf2 + bf2)
    gemm_bf16<<<dim3(4, NA_ * T_ / 64), blk, 0, stream>>>(
        F1b, wf2t, bf2, nullptr, nullptr, nullptr,
        F2, nullptr, nullptr, nullptr, NA_ * T_, 256, 1024, 4);

    ln_apply<<<dim3(NA_ * T_ / 4), blk, 0, stream>>>(F2, ln_z_g, ln_z_b, Z);
}

// Round 5
// 302.096 us; speedup vs baseline: 6.3958x; 1.1307x over previous
//
#include <hip/hip_runtime.h>

#define T_   91
#define D_   256
#define H_   4
#define DH_  64
#define NA_  128
#define NRG_ 1024
#define KEXP_ 4

typedef float f32x4 __attribute__((ext_vector_type(4)));
typedef short bf16x8 __attribute__((ext_vector_type(8)));

static constexpr float P_EPS = 1.3877787807814457e-17f;  // 2^-56, exact in bf16

__device__ inline ushort f2bf(float f) {
    union { float f; unsigned u; } v; v.f = f;
    unsigned r = (v.u + 0x7fffu + ((v.u >> 16) & 1u)) >> 16;
    return (ushort)r;
}
__device__ inline unsigned pk2(float a, float b) {
    return (unsigned)f2bf(a) | ((unsigned)f2bf(b) << 16);
}
__device__ inline float bf2f(ushort b) {
    union { unsigned u; float f; } v; v.u = ((unsigned)b) << 16;
    return v.f;
}

// ---------------------------------------------------------------------------
// LayerNorm + bf16 convert: ONE WAVE per 256-elem row, f32x4 + shfl reduce.
// ---------------------------------------------------------------------------
__global__ __launch_bounds__(256) void ln_norm(
    const float* __restrict__ agent, const float* __restrict__ rg,
    const float* __restrict__ g, const float* __restrict__ b,
    ushort* __restrict__ agn, ushort* __restrict__ rgn) {
    int row = blockIdx.x * 4 + (threadIdx.x >> 6);
    int lane = threadIdx.x & 63;
    bool is_a = row < NA_ * T_;
    const float* src = is_a ? (agent + (size_t)row * D_)
                            : (rg + (size_t)(row - NA_ * T_) * D_);
    f32x4 x = *(const f32x4*)(src + lane * 4);
    float s1 = x[0] + x[1] + x[2] + x[3];
    float s2 = x[0] * x[0] + x[1] * x[1] + x[2] * x[2] + x[3] * x[3];
#pragma unroll
    for (int off = 1; off < 64; off <<= 1) {
        s1 += __shfl_xor(s1, off);
        s2 += __shfl_xor(s2, off);
    }
    float mean = s1 * (1.0f / 256.0f);
    float var = s2 * (1.0f / 256.0f) - mean * mean;
    float rstd = rsqrtf(var + 1e-5f);
    f32x4 gv = *(const f32x4*)(g + lane * 4);
    f32x4 bv = *(const f32x4*)(b + lane * 4);
    float y0 = (x[0] - mean) * rstd * gv[0] + bv[0];
    float y1 = (x[1] - mean) * rstd * gv[1] + bv[1];
    float y2 = (x[2] - mean) * rstd * gv[2] + bv[2];
    float y3 = (x[3] - mean) * rstd * gv[3] + bv[3];
    ushort* dst = is_a ? (agn + (size_t)row * D_)
                       : (rgn + (size_t)(row - NA_ * T_) * D_);
    *(uint2*)(dst + lane * 4) = make_uint2(pk2(y0, y1), pk2(y2, y3));
}

// ---------------------------------------------------------------------------
// Weight transpose + bf16 convert: dst[n][k] = bf16(W[k][n])
// ---------------------------------------------------------------------------
__global__ void prep_w(const float* __restrict__ W, ushort* __restrict__ dst,
                       int K, int N) {
    int idx = blockIdx.x * 256 + threadIdx.x;
    int n = idx / K, k = idx % K;
    dst[idx] = f2bf(W[(size_t)k * N + n]);
}

// ---------------------------------------------------------------------------
// Mask bit-pack: cm[(t*NA+a)*32 + w], bit r&31 of word r>>5.
// ---------------------------------------------------------------------------
__global__ __launch_bounds__(256) void pack_mask(
    const int* __restrict__ am, const int* __restrict__ pm,
    const int* __restrict__ vmk, unsigned* __restrict__ cm) {
    int base = blockIdx.x * 4;
    int t = base / NA_;
    int w = threadIdx.x >> 6, lane = threadIdx.x & 63;
    __shared__ int pmS[NRG_];
#pragma unroll
    for (int i = 0; i < 4; ++i)
        pmS[threadIdx.x + i * 256] = pm[(size_t)t * NRG_ + threadIdx.x + i * 256];
    __syncthreads();
    int idx = base + w;
    int a = idx & (NA_ - 1);
    int valid = vmk[t * NA_ + a];
    const int* amrow = am + (size_t)idx * NRG_;
#pragma unroll
    for (int c = 0; c < 16; ++c) {
        int r = c * 64 + lane;
        bool bit = valid && amrow[r] && pmS[r];
        unsigned long long msk = __ballot(bit);
        if (lane == 0) {
            cm[(size_t)idx * 32 + c * 2]     = (unsigned)msk;
            cm[(size_t)idx * 32 + c * 2 + 1] = (unsigned)(msk >> 32);
        }
    }
}

// ---------------------------------------------------------------------------
// Wide bf16 MFMA GEMM: BM=64, BN=256, 512 threads (8 waves, 2x4).
// A: M x K bf16; Bt: N x K bf16. grid (N/256, M/64).
// mode 1 (KV): bxi=0 -> K (out0=Kp f32, out2=Kb bf16, (t,h,r,d));
//              bxi=1 -> V (out1=Vp f32, out3=Vtb bf16 transposed (t,h,d,r)).
//              M order is t-major: tile = fixed t, rr in [rb, rb+64).
// mode 2 (Q): t-major over NA; out0=Qp f32 (t,h,a,d), out2=Qb bf16 (x0.5);
//              v *= aux0[d] (q_scale).
// mode 3 (S): natural; v += bf16 residb; out2 bf16 row-major.
// mode 0 (F1): natural; out2 bf16 row-major.
// mode 5 (F2+LN): natural; K=1024; LN over N=256 in epilogue
//              (gamma=bias1, beta=aux0); out0 = Z f32 row-major.
// ---------------------------------------------------------------------------
__global__ __launch_bounds__(512) void gemm_wide(
    const ushort* __restrict__ Ab, const ushort* __restrict__ Bt,
    const float* __restrict__ bias0, const float* __restrict__ bias1,
    const float* __restrict__ aux0, const ushort* __restrict__ residb,
    float* __restrict__ out0, float* __restrict__ out1,
    ushort* __restrict__ out2, ushort* __restrict__ out3,
    int N, int K, int mode) {
    __shared__ ushort smem[64 * 72 + 256 * 72];
    __shared__ float lnp[2][64][4];
    ushort (*As)[72] = (ushort(*)[72])smem;
    ushort (*Bs)[72] = (ushort(*)[72])(smem + 64 * 72);
    float (*Et)[68] = (float(*)[68])smem;

    int bxi = blockIdx.x, by = blockIdx.y;
    int bn = bxi * 256;
    int bm = by * 64;
    int t = 0, rb = 0, a0 = 0;
    if (mode == 1) { t = by >> 4; rb = (by & 15) << 6; }
    else if (mode == 2) { t = by >> 1; a0 = (by & 1) << 6; }

    int tid = threadIdx.x;
    int w = tid >> 6, lane = tid & 63;
    int wm = w >> 2, wn = w & 3;
    int l15 = lane & 15, l4 = lane >> 4;

    f32x4 acc[2][4];
#pragma unroll
    for (int i = 0; i < 2; ++i)
#pragma unroll
        for (int j = 0; j < 4; ++j)
#pragma unroll
            for (int r = 0; r < 4; ++r) acc[i][j][r] = 0.0f;

    for (int k0 = 0; k0 < K; k0 += 64) {
        {
            int row = tid >> 3, c8 = (tid & 7) * 8;
            size_t arow = (mode == 1) ? ((size_t)(rb + row) * T_ + t)
                        : (mode == 2) ? ((size_t)(a0 + row) * T_ + t)
                        : (size_t)(bm + row);
            *(bf16x8*)&As[row][c8] = *(const bf16x8*)(Ab + arow * K + k0 + c8);
        }
#pragma unroll
        for (int it = 0; it < 4; ++it) {
            int li = tid + it * 512;
            int row = li >> 3, c8 = (li & 7) * 8;
            *(bf16x8*)&Bs[row][c8] =
                *(const bf16x8*)(Bt + (size_t)(bn + row) * K + k0 + c8);
        }
        __syncthreads();
#pragma unroll
        for (int kk = 0; kk < 2; ++kk) {
            bf16x8 af[2], bfr[4];
#pragma unroll
            for (int i = 0; i < 2; ++i)
                af[i] = *(const bf16x8*)&As[wm * 32 + i * 16 + l15][kk * 32 + l4 * 8];
#pragma unroll
            for (int j = 0; j < 4; ++j)
                bfr[j] = *(const bf16x8*)&Bs[wn * 64 + j * 16 + l15][kk * 32 + l4 * 8];
#pragma unroll
            for (int i = 0; i < 2; ++i)
#pragma unroll
                for (int j = 0; j < 4; ++j)
                    acc[i][j] = __builtin_amdgcn_mfma_f32_16x16x32_bf16(
                        af[i], bfr[j], acc[i][j], 0, 0, 0);
        }
        __syncthreads();
    }

    // ---- epilogue values in regs ----
    float v[2][4][4];
#pragma unroll
    for (int i = 0; i < 2; ++i)
#pragma unroll
        for (int j = 0; j < 4; ++j)
#pragma unroll
            for (int reg = 0; reg < 4; ++reg) {
                int nl = wn * 64 + j * 16 + l15;
                int rowl = wm * 32 + i * 16 + l4 * 4 + reg;
                float bs;
                if (mode == 1) bs = bxi ? bias1[nl] : bias0[nl];
                else if (mode == 0) bs = bias0[bn + nl];
                else bs = bias0[nl];
                float x = fmaxf(acc[i][j][reg] + bs, 0.0f);
                if (mode == 2) x *= aux0[nl & 63];
                if (mode == 3) x += bf2f(residb[(size_t)(bm + rowl) * 256 + nl]);
                v[i][j][reg] = x;
            }

    if (mode == 5) {
        // row-wise LN over N=256: shfl over l15, cross-wn via LDS partials
        float rs_[2][4], rq_[2][4];
#pragma unroll
        for (int i = 0; i < 2; ++i)
#pragma unroll
            for (int reg = 0; reg < 4; ++reg) {
                float s = 0.0f, q = 0.0f;
#pragma unroll
                for (int j = 0; j < 4; ++j) {
                    float x = v[i][j][reg];
                    s += x; q += x * x;
                }
#pragma unroll
                for (int off = 1; off < 16; off <<= 1) {
                    s += __shfl_xor(s, off);
                    q += __shfl_xor(q, off);
                }
                rs_[i][reg] = s; rq_[i][reg] = q;
            }
        if (l15 == 0) {
#pragma unroll
            for (int i = 0; i < 2; ++i)
#pragma unroll
                for (int reg = 0; reg < 4; ++reg) {
                    int row = wm * 32 + i * 16 + l4 * 4 + reg;
                    lnp[0][row][wn] = rs_[i][reg];
                    lnp[1][row][wn] = rq_[i][reg];
                }
        }
        __syncthreads();
#pragma unroll
        for (int i = 0; i < 2; ++i)
#pragma unroll
            for (int reg = 0; reg < 4; ++reg) {
                int row = wm * 32 + i * 16 + l4 * 4 + reg;
                float S1 = lnp[0][row][0] + lnp[0][row][1] + lnp[0][row][2] + lnp[0][row][3];
                float S2 = lnp[1][row][0] + lnp[1][row][1] + lnp[1][row][2] + lnp[1][row][3];
                float mean = S1 * (1.0f / 256.0f);
                float var = S2 * (1.0f / 256.0f) - mean * mean;
                float rstd = rsqrtf(var + 1e-5f);
#pragma unroll
                for (int j = 0; j < 4; ++j) {
                    int nl = wn * 64 + j * 16 + l15;
                    float z = (v[i][j][reg] - mean) * rstd * bias1[nl] + aux0[nl];
                    out0[(size_t)(bm + row) * 256 + nl] = z;
                }
            }
        return;
    }

    // ---- staged epilogue: 4 rounds of 64-col chunks ----
#pragma unroll 1
    for (int jq = 0; jq < 4; ++jq) {
        __syncthreads();
        if (wn == jq) {
#pragma unroll
            for (int i = 0; i < 2; ++i)
#pragma unroll
                for (int j = 0; j < 4; ++j)
#pragma unroll
                    for (int reg = 0; reg < 4; ++reg)
                        Et[wm * 32 + i * 16 + l4 * 4 + reg][j * 16 + l15] = v[i][j][reg];
        }
        __syncthreads();

        if (mode == 1) {
            size_t base = (((size_t)t * H_ + jq) * NRG_ + rb) * DH_;
            float* of = bxi ? out1 : out0;
#pragma unroll
            for (int it = 0; it < 2; ++it) {
                int slot = it * 512 + tid;
                int row = slot >> 4, c4 = (slot & 15) * 4;
                *(f32x4*)(of + base + row * 64 + c4) = *(f32x4*)&Et[row][c4];
            }
            if (!bxi) {
#pragma unroll
                for (int it = 0; it < 2; ++it) {
                    int slot = it * 512 + tid;
                    int row = slot >> 4, c4 = (slot & 15) * 4;
                    uint2 u = make_uint2(pk2(Et[row][c4], Et[row][c4 + 1]),
                                         pk2(Et[row][c4 + 2], Et[row][c4 + 3]));
                    *(uint2*)(out2 + base + row * 64 + c4) = u;
                }
            } else {
                __syncthreads();
                if (wn == jq) {
#pragma unroll
                    for (int i = 0; i < 2; ++i)
#pragma unroll
                        for (int j = 0; j < 4; ++j)
#pragma unroll
                            for (int reg = 0; reg < 4; ++reg)
                                Et[j * 16 + l15][wm * 32 + i * 16 + l4 * 4 + reg] = v[i][j][reg];
                }
                __syncthreads();
                size_t tb = ((size_t)t * H_ + jq) * DH_ * NRG_;
#pragma unroll
                for (int it = 0; it < 2; ++it) {
                    int slot = it * 512 + tid;
                    int d = slot >> 4, r4 = (slot & 15) * 4;
                    uint2 u = make_uint2(pk2(Et[d][r4], Et[d][r4 + 1]),
                                         pk2(Et[d][r4 + 2], Et[d][r4 + 3]));
                    *(uint2*)(out3 + tb + (size_t)d * NRG_ + rb + r4) = u;
                }
            }
        } else if (mode == 2) {
            size_t base = (((size_t)t * H_ + jq) * NA_ + a0) * DH_;
#pragma unroll
            for (int it = 0; it < 2; ++it) {
                int slot = it * 512 + tid;
                int row = slot >> 4, c4 = (slot & 15) * 4;
                *(f32x4*)(out0 + base + row * 64 + c4) = *(f32x4*)&Et[row][c4];
                uint2 u = make_uint2(pk2(Et[row][c4] * 0.5f, Et[row][c4 + 1] * 0.5f),
                                     pk2(Et[row][c4 + 2] * 0.5f, Et[row][c4 + 3] * 0.5f));
                *(uint2*)(out2 + base + row * 64 + c4) = u;
            }
        } else {  // mode 0 / 3: bf16 row-major
#pragma unroll
            for (int it = 0; it < 2; ++it) {
                int slot = it * 512 + tid;
                int row = slot >> 4, c4 = (slot & 15) * 4;
                uint2 u = make_uint2(pk2(Et[row][c4], Et[row][c4 + 1]),
                                     pk2(Et[row][c4 + 2], Et[row][c4 + 3]));
                *(uint2*)(out2 + (size_t)(bm + row) * N + bn + jq * 64 + c4) = u;
            }
        }
    }
}

// ---------------------------------------------------------------------------
// Flash attention: grid(2, T*H). 4 waves; wave owns 16 a-rows.
// No online max (Q,K >= 0, e in [0,~1]); masked -> P_EPS.
// ---------------------------------------------------------------------------
__global__ __launch_bounds__(256) void attn_flash(
    const ushort* __restrict__ Qb, const ushort* __restrict__ Kb,
    const ushort* __restrict__ Vtb, const unsigned* __restrict__ cm,
    ushort* __restrict__ Y1b) {
    int ah = blockIdx.x;
    int th = blockIdx.y;
    int t = th >> 2, h = th & 3;
    int tid = threadIdx.x;
    int w = tid >> 6, lane = tid & 63;
    int l15 = lane & 15, l4 = lane >> 4;

    __shared__ ushort Ks[64][72];
    __shared__ ushort Vts[64][72];
    __shared__ ushort Ps[64][72];
    __shared__ unsigned cmw[64][2];

    bf16x8 qf[2];
#pragma unroll
    for (int kk = 0; kk < 2; ++kk)
        qf[kk] = *(const bf16x8*)(Qb + ((size_t)th * NA_ + ah * 64 + w * 16 + l15) * DH_
                                  + kk * 32 + l4 * 8);

    f32x4 o[4];
    float rsum[4] = {0.0f, 0.0f, 0.0f, 0.0f};
#pragma unroll
    for (int ds = 0; ds < 4; ++ds)
#pragma unroll
        for (int r = 0; r < 4; ++r) o[ds][r] = 0.0f;

    for (int rt = 0; rt < 16; ++rt) {
        int r0 = rt * 64;
#pragma unroll
        for (int it = 0; it < 2; ++it) {
            int li = tid + it * 256;
            int row = li >> 3, c8 = (li & 7) * 8;
            *(bf16x8*)&Ks[row][c8] =
                *(const bf16x8*)(Kb + ((size_t)th * NRG_ + r0 + row) * DH_ + c8);
            *(bf16x8*)&Vts[row][c8] =
                *(const bf16x8*)(Vtb + ((size_t)th * DH_ + row) * NRG_ + r0 + c8);
        }
        if (tid < 128) {
            int a = tid >> 1, wd = tid & 1;
            cmw[a][wd] = cm[((size_t)t * NA_ + ah * 64 + a) * 32 + rt * 2 + wd];
        }
        __syncthreads();

        f32x4 e[4];
#pragma unroll
        for (int rs = 0; rs < 4; ++rs) {
#pragma unroll
            for (int r = 0; r < 4; ++r) e[rs][r] = 0.0f;
#pragma unroll
            for (int kk = 0; kk < 2; ++kk) {
                bf16x8 kf = *(const bf16x8*)&Ks[rs * 16 + l15][kk * 32 + l4 * 8];
                e[rs] = __builtin_amdgcn_mfma_f32_16x16x32_bf16(qf[kk], kf, e[rs], 0, 0, 0);
            }
        }

#pragma unroll
        for (int reg = 0; reg < 4; ++reg) {
            int a_loc = w * 16 + l4 * 4 + reg;
            unsigned w0 = cmw[a_loc][0], w1 = cmw[a_loc][1];
#pragma unroll
            for (int rs = 0; rs < 4; ++rs) {
                unsigned wd = (rs & 2) ? w1 : w0;
                int bit = (wd >> ((rs & 1) * 16 + l15)) & 1;
                float p = bit ? __expf(e[rs][reg]) : P_EPS;
                rsum[reg] += p;
                Ps[a_loc][rs * 16 + l15] = f2bf(p);
            }
        }

#pragma unroll
        for (int rc = 0; rc < 2; ++rc) {
            bf16x8 pa = *(const bf16x8*)&Ps[w * 16 + l15][rc * 32 + l4 * 8];
#pragma unroll
            for (int ds = 0; ds < 4; ++ds) {
                bf16x8 vf = *(const bf16x8*)&Vts[ds * 16 + l15][rc * 32 + l4 * 8];
                o[ds] = __builtin_amdgcn_mfma_f32_16x16x32_bf16(pa, vf, o[ds], 0, 0, 0);
            }
        }
        __syncthreads();
    }

#pragma unroll
    for (int off = 1; off < 16; off <<= 1)
#pragma unroll
        for (int reg = 0; reg < 4; ++reg)
            rsum[reg] += __shfl_xor(rsum[reg], off);
    float rinv[4];
#pragma unroll
    for (int reg = 0; reg < 4; ++reg) rinv[reg] = 1.0f / rsum[reg];

#pragma unroll
    for (int ds = 0; ds < 4; ++ds)
#pragma unroll
        for (int reg = 0; reg < 4; ++reg) {
            int a_g = ah * 64 + w * 16 + l4 * 4 + reg;
            int d = ds * 16 + l15;
            Y1b[((size_t)a_g * T_ + t) * D_ + h * DH_ + d] = f2bf(o[ds][reg] * rinv[reg]);
        }
}

// ---------------------------------------------------------------------------
extern "C" void kernel_launch(void* const* d_in, const int* in_sizes, int n_in,
                              void* d_out, int out_size, void* d_ws, size_t ws_size,
                              hipStream_t stream) {
    const float* agent   = (const float*)d_in[0];
    const float* rg      = (const float*)d_in[1];
    const float* ln_x_g  = (const float*)d_in[2];
    const float* ln_x_b  = (const float*)d_in[3];
    const float* wk      = (const float*)d_in[4];
    const float* bk      = (const float*)d_in[5];
    const float* wv      = (const float*)d_in[6];
    const float* bv      = (const float*)d_in[7];
    const float* wq      = (const float*)d_in[8];
    const float* bq      = (const float*)d_in[9];
    const float* q_scale = (const float*)d_in[10];
    const float* wy      = (const float*)d_in[11];
    const float* by      = (const float*)d_in[12];
    const float* wf1     = (const float*)d_in[13];
    const float* bf1     = (const float*)d_in[14];
    const float* wf2     = (const float*)d_in[15];
    const float* bf2     = (const float*)d_in[16];
    const float* ln_z_g  = (const float*)d_in[17];
    const float* ln_z_b  = (const float*)d_in[18];
    const int*   am      = (const int*)d_in[19];
    const int*   pm      = (const int*)d_in[20];
    const int*   vmk     = (const int*)d_in[21];

    float* Z  = (float*)d_out;
    float* Qp = Z + (size_t)NA_ * T_ * D_;
    float* Kp = Qp + (size_t)NA_ * T_ * D_;
    float* Vp = Kp + (size_t)NRG_ * T_ * D_;

    char* p = (char*)d_ws;
    ushort* rgn_b = (ushort*)p;   p += (size_t)NRG_ * T_ * D_ * 2;   // aliased by F1b
    ushort* agn_b = (ushort*)p;   p += (size_t)NA_ * T_ * D_ * 2;
    ushort* wkvt  = (ushort*)p;   p += (size_t)512 * 256 * 2;
    ushort* wqt   = (ushort*)p;   p += (size_t)256 * 256 * 2;
    ushort* wyt   = (ushort*)p;   p += (size_t)256 * 256 * 2;
    ushort* wf1t  = (ushort*)p;   p += (size_t)1024 * 256 * 2;
    ushort* wf2t  = (ushort*)p;   p += (size_t)256 * 1024 * 2;
    unsigned* cm  = (unsigned*)p; p += (size_t)T_ * NA_ * 32 * 4;
    ushort* Kb    = (ushort*)p;   p += (size_t)T_ * H_ * NRG_ * DH_ * 2;
    ushort* Vtb   = (ushort*)p;   p += (size_t)T_ * H_ * NRG_ * DH_ * 2;
    ushort* Qb    = (ushort*)p;   p += (size_t)T_ * H_ * NA_ * DH_ * 2;
    ushort* Y1b   = (ushort*)p;   p += (size_t)NA_ * T_ * D_ * 2;
    ushort* Sb    = (ushort*)p;   p += (size_t)NA_ * T_ * D_ * 2;

    ushort* F1b = rgn_b;          // alias: rgn dead after KV/Q GEMMs

    dim3 blk(256), wblk(512);

    ln_norm<<<dim3((NA_ + NRG_) * T_ / 4), blk, 0, stream>>>(
        agent, rg, ln_x_g, ln_x_b, agn_b, rgn_b);

    prep_w<<<dim3(256), blk, 0, stream>>>(wk, wkvt, 256, 256);
    prep_w<<<dim3(256), blk, 0, stream>>>(wv, wkvt + 65536, 256, 256);
    prep_w<<<dim3(256), blk, 0, stream>>>(wq, wqt, 256, 256);
    prep_w<<<dim3(256), blk, 0, stream>>>(wy, wyt, 256, 256);
    prep_w<<<dim3(1024), blk, 0, stream>>>(wf1, wf1t, 256, 1024);
    prep_w<<<dim3(1024), blk, 0, stream>>>(wf2, wf2t, 1024, 256);

    pack_mask<<<dim3(T_ * NA_ / 4), blk, 0, stream>>>(am, pm, vmk, cm);

    // K|V fused (t-major M): grid (2, 91*16)
    gemm_wide<<<dim3(2, T_ * 16), wblk, 0, stream>>>(
        rgn_b, wkvt, bk, bv, nullptr, nullptr,
        Kp, Vp, Kb, Vtb, 512, 256, 1);

    // Q (t-major M): grid (1, 91*2)
    gemm_wide<<<dim3(1, T_ * 2), wblk, 0, stream>>>(
        agn_b, wqt, bq, nullptr, q_scale, nullptr,
        Qp, nullptr, Qb, nullptr, 256, 256, 2);

    attn_flash<<<dim3(2, T_ * H_), blk, 0, stream>>>(Qb, Kb, Vtb, cm, Y1b);

    // S = relu(Y1 @ wy + by) + agent_n
    gemm_wide<<<dim3(1, NA_ * T_ / 64), wblk, 0, stream>>>(
        Y1b, wyt, by, nullptr, nullptr, agn_b,
        nullptr, nullptr, Sb, nullptr, 256, 256, 3);

    // F1 = relu(S @ wf1 + bf1)
    gemm_wide<<<dim3(4, NA_ * T_ / 64), wblk, 0, stream>>>(
        Sb, wf1t, bf1, nullptr, nullptr, nullptr,
        nullptr, nullptr, F1b, nullptr, 1024, 256, 0);

    // Z = ln(relu(F1 @ wf2 + bf2))
    gemm_wide<<<dim3(1, NA_ * T_ / 64), wblk, 0, stream>>>(
        F1b, wf2t, bf2, ln_z_g, ln_z_b, nullptr,
        Z, nullptr, nullptr, nullptr, 256, 1024, 5);
}

// Round 6
// 291.962 us; speedup vs baseline: 6.6178x; 1.0347x over previous
//
#include <hip/hip_runtime.h>

#define T_   91
#define D_   256
#define H_   4
#define DH_  64
#define NA_  128
#define NRG_ 1024
#define KEXP_ 4

typedef float f32x4 __attribute__((ext_vector_type(4)));
typedef short bf16x8 __attribute__((ext_vector_type(8)));

static constexpr float P_EPS = 1.3877787807814457e-17f;  // 2^-56, exact in bf16

__device__ inline ushort f2bf(float f) {
    union { float f; unsigned u; } v; v.f = f;
    unsigned r = (v.u + 0x7fffu + ((v.u >> 16) & 1u)) >> 16;
    return (ushort)r;
}
__device__ inline unsigned pk2(float a, float b) {
    return (unsigned)f2bf(a) | ((unsigned)f2bf(b) << 16);
}
__device__ inline float bf2f(ushort b) {
    union { unsigned u; float f; } v; v.u = ((unsigned)b) << 16;
    return v.f;
}

// ---------------------------------------------------------------------------
// LayerNorm + bf16 convert: ONE WAVE per 256-elem row, f32x4 + shfl reduce.
// ---------------------------------------------------------------------------
__global__ __launch_bounds__(256) void ln_norm(
    const float* __restrict__ agent, const float* __restrict__ rg,
    const float* __restrict__ g, const float* __restrict__ b,
    ushort* __restrict__ agn, ushort* __restrict__ rgn) {
    int row = blockIdx.x * 4 + (threadIdx.x >> 6);
    int lane = threadIdx.x & 63;
    bool is_a = row < NA_ * T_;
    const float* src = is_a ? (agent + (size_t)row * D_)
                            : (rg + (size_t)(row - NA_ * T_) * D_);
    f32x4 x = *(const f32x4*)(src + lane * 4);
    float s1 = x[0] + x[1] + x[2] + x[3];
    float s2 = x[0] * x[0] + x[1] * x[1] + x[2] * x[2] + x[3] * x[3];
#pragma unroll
    for (int off = 1; off < 64; off <<= 1) {
        s1 += __shfl_xor(s1, off);
        s2 += __shfl_xor(s2, off);
    }
    float mean = s1 * (1.0f / 256.0f);
    float var = s2 * (1.0f / 256.0f) - mean * mean;
    float rstd = rsqrtf(var + 1e-5f);
    f32x4 gv = *(const f32x4*)(g + lane * 4);
    f32x4 bv = *(const f32x4*)(b + lane * 4);
    float y0 = (x[0] - mean) * rstd * gv[0] + bv[0];
    float y1 = (x[1] - mean) * rstd * gv[1] + bv[1];
    float y2 = (x[2] - mean) * rstd * gv[2] + bv[2];
    float y3 = (x[3] - mean) * rstd * gv[3] + bv[3];
    ushort* dst = is_a ? (agn + (size_t)row * D_)
                       : (rgn + (size_t)(row - NA_ * T_) * D_);
    *(uint2*)(dst + lane * 4) = make_uint2(pk2(y0, y1), pk2(y2, y3));
}

// ---------------------------------------------------------------------------
// All weight transposes in ONE launch. dst[n][k] = bf16(W[k][n]).
// Ranges (256-elem granularity): wk,wv,wq,wy (65536 each), wf1, wf2 (262144).
// ---------------------------------------------------------------------------
__global__ __launch_bounds__(256) void prep_w_all(
    const float* __restrict__ wk, const float* __restrict__ wv,
    const float* __restrict__ wq, const float* __restrict__ wy,
    const float* __restrict__ wf1, const float* __restrict__ wf2,
    ushort* __restrict__ wkvt, ushort* __restrict__ wqt,
    ushort* __restrict__ wyt, ushort* __restrict__ wf1t,
    ushort* __restrict__ wf2t) {
    int idx = blockIdx.x * 256 + threadIdx.x;
    if (idx < 131072) {  // wk | wv -> wkvt (512 x 256)
        const float* W = (idx < 65536) ? wk : wv;
        int li = idx & 65535;
        int n = li >> 8, k = li & 255;
        wkvt[idx] = f2bf(W[(size_t)k * 256 + n]);
    } else if (idx < 196608) {
        int li = idx - 131072;
        int n = li >> 8, k = li & 255;
        wqt[li] = f2bf(wq[(size_t)k * 256 + n]);
    } else if (idx < 262144) {
        int li = idx - 196608;
        int n = li >> 8, k = li & 255;
        wyt[li] = f2bf(wy[(size_t)k * 256 + n]);
    } else if (idx < 524288) {
        int li = idx - 262144;           // N=1024, K=256
        int n = li >> 8, k = li & 255;
        wf1t[li] = f2bf(wf1[(size_t)k * 1024 + n]);
    } else {
        int li = idx - 524288;           // N=256, K=1024
        int n = li >> 10, k = li & 1023;
        wf2t[li] = f2bf(wf2[(size_t)k * 256 + n]);
    }
}

// ---------------------------------------------------------------------------
// Mask bit-pack: cm[(t*NA+a)*32 + w], bit r&31 of word r>>5.
// ---------------------------------------------------------------------------
__global__ __launch_bounds__(256) void pack_mask(
    const int* __restrict__ am, const int* __restrict__ pm,
    const int* __restrict__ vmk, unsigned* __restrict__ cm) {
    int base = blockIdx.x * 4;
    int t = base / NA_;
    int w = threadIdx.x >> 6, lane = threadIdx.x & 63;
    __shared__ int pmS[NRG_];
#pragma unroll
    for (int i = 0; i < 4; ++i)
        pmS[threadIdx.x + i * 256] = pm[(size_t)t * NRG_ + threadIdx.x + i * 256];
    __syncthreads();
    int idx = base + w;
    int a = idx & (NA_ - 1);
    int valid = vmk[t * NA_ + a];
    const int* amrow = am + (size_t)idx * NRG_;
#pragma unroll
    for (int c = 0; c < 16; ++c) {
        int r = c * 64 + lane;
        bool bit = valid && amrow[r] && pmS[r];
        unsigned long long msk = __ballot(bit);
        if (lane == 0) {
            cm[(size_t)idx * 32 + c * 2]     = (unsigned)msk;
            cm[(size_t)idx * 32 + c * 2 + 1] = (unsigned)(msk >> 32);
        }
    }
}

// ---------------------------------------------------------------------------
// Wide bf16 MFMA GEMM: BM=64, BN=256, 512 threads (8 waves, 2x4).
// mode 1 (KV): 1D grid 2912, XCD-paired remap (K-block and V-block of the
//              same tile land on the same XCD -> A-tile L2 reuse).
//              bxi=0 -> K (out0=Kp f32, out2=Kb bf16, (t,h,r,d));
//              bxi=1 -> V (out1=Vp f32, out3=Vtb bf16 (t,h,d,r)).
// mode 2 (Q): t-major over NA; out0=Qp f32 (t,h,a,d), out2=Qb bf16 (x0.5);
//              v *= aux0[d] (q_scale).
// mode 3 (S): natural; v += bf16 residb; out2 bf16 row-major.
// mode 0 (F1): natural; out2 bf16 row-major.
// mode 5 (F2+LN): natural; K=1024; LN over N=256 in epilogue
//              (gamma=bias1, beta=aux0); out0 = Z f32 row-major.
// ---------------------------------------------------------------------------
__global__ __launch_bounds__(512) void gemm_wide(
    const ushort* __restrict__ Ab, const ushort* __restrict__ Bt,
    const float* __restrict__ bias0, const float* __restrict__ bias1,
    const float* __restrict__ aux0, const ushort* __restrict__ residb,
    float* __restrict__ out0, float* __restrict__ out1,
    ushort* __restrict__ out2, ushort* __restrict__ out3,
    int N, int K, int mode) {
    __shared__ ushort smem[64 * 72 + 256 * 72];
    __shared__ float lnp[2][64][4];
    ushort (*As)[72] = (ushort(*)[72])smem;
    ushort (*Bs)[72] = (ushort(*)[72])(smem + 64 * 72);
    float (*Et)[68] = (float(*)[68])smem;

    int bxi, by;
    if (mode == 1) {
        int wg = blockIdx.x;            // 2912 = 182 * 16
        int sub = wg & 15, pid = wg >> 4;
        bxi = sub >> 3;
        by = pid * 8 + (sub & 7);       // pair (bxi=0,1) differs by 8 -> same XCD
    } else {
        bxi = blockIdx.x; by = blockIdx.y;
    }
    int bn = bxi * 256;
    int bm = by * 64;
    int t = 0, rb = 0, a0 = 0;
    if (mode == 1) { t = by >> 4; rb = (by & 15) << 6; }
    else if (mode == 2) { t = by >> 1; a0 = (by & 1) << 6; }

    int tid = threadIdx.x;
    int w = tid >> 6, lane = tid & 63;
    int wm = w >> 2, wn = w & 3;
    int l15 = lane & 15, l4 = lane >> 4;

    f32x4 acc[2][4];
#pragma unroll
    for (int i = 0; i < 2; ++i)
#pragma unroll
        for (int j = 0; j < 4; ++j)
#pragma unroll
            for (int r = 0; r < 4; ++r) acc[i][j][r] = 0.0f;

    for (int k0 = 0; k0 < K; k0 += 64) {
        {
            int row = tid >> 3, c8 = (tid & 7) * 8;
            size_t arow = (mode == 1) ? ((size_t)(rb + row) * T_ + t)
                        : (mode == 2) ? ((size_t)(a0 + row) * T_ + t)
                        : (size_t)(bm + row);
            *(bf16x8*)&As[row][c8] = *(const bf16x8*)(Ab + arow * K + k0 + c8);
        }
#pragma unroll
        for (int it = 0; it < 4; ++it) {
            int li = tid + it * 512;
            int row = li >> 3, c8 = (li & 7) * 8;
            *(bf16x8*)&Bs[row][c8] =
                *(const bf16x8*)(Bt + (size_t)(bn + row) * K + k0 + c8);
        }
        __syncthreads();
#pragma unroll
        for (int kk = 0; kk < 2; ++kk) {
            bf16x8 af[2], bfr[4];
#pragma unroll
            for (int i = 0; i < 2; ++i)
                af[i] = *(const bf16x8*)&As[wm * 32 + i * 16 + l15][kk * 32 + l4 * 8];
#pragma unroll
            for (int j = 0; j < 4; ++j)
                bfr[j] = *(const bf16x8*)&Bs[wn * 64 + j * 16 + l15][kk * 32 + l4 * 8];
#pragma unroll
            for (int i = 0; i < 2; ++i)
#pragma unroll
                for (int j = 0; j < 4; ++j)
                    acc[i][j] = __builtin_amdgcn_mfma_f32_16x16x32_bf16(
                        af[i], bfr[j], acc[i][j], 0, 0, 0);
        }
        __syncthreads();
    }

    // ---- epilogue values in regs ----
    float v[2][4][4];
#pragma unroll
    for (int i = 0; i < 2; ++i)
#pragma unroll
        for (int j = 0; j < 4; ++j)
#pragma unroll
            for (int reg = 0; reg < 4; ++reg) {
                int nl = wn * 64 + j * 16 + l15;
                int rowl = wm * 32 + i * 16 + l4 * 4 + reg;
                float bs;
                if (mode == 1) bs = bxi ? bias1[nl] : bias0[nl];
                else if (mode == 0) bs = bias0[bn + nl];
                else bs = bias0[nl];
                float x = fmaxf(acc[i][j][reg] + bs, 0.0f);
                if (mode == 2) x *= aux0[nl & 63];
                if (mode == 3) x += bf2f(residb[(size_t)(bm + rowl) * 256 + nl]);
                v[i][j][reg] = x;
            }

    if (mode == 5) {
        float rs_[2][4], rq_[2][4];
#pragma unroll
        for (int i = 0; i < 2; ++i)
#pragma unroll
            for (int reg = 0; reg < 4; ++reg) {
                float s = 0.0f, q = 0.0f;
#pragma unroll
                for (int j = 0; j < 4; ++j) {
                    float x = v[i][j][reg];
                    s += x; q += x * x;
                }
#pragma unroll
                for (int off = 1; off < 16; off <<= 1) {
                    s += __shfl_xor(s, off);
                    q += __shfl_xor(q, off);
                }
                rs_[i][reg] = s; rq_[i][reg] = q;
            }
        if (l15 == 0) {
#pragma unroll
            for (int i = 0; i < 2; ++i)
#pragma unroll
                for (int reg = 0; reg < 4; ++reg) {
                    int row = wm * 32 + i * 16 + l4 * 4 + reg;
                    lnp[0][row][wn] = rs_[i][reg];
                    lnp[1][row][wn] = rq_[i][reg];
                }
        }
        __syncthreads();
#pragma unroll
        for (int i = 0; i < 2; ++i)
#pragma unroll
            for (int reg = 0; reg < 4; ++reg) {
                int row = wm * 32 + i * 16 + l4 * 4 + reg;
                float S1 = lnp[0][row][0] + lnp[0][row][1] + lnp[0][row][2] + lnp[0][row][3];
                float S2 = lnp[1][row][0] + lnp[1][row][1] + lnp[1][row][2] + lnp[1][row][3];
                float mean = S1 * (1.0f / 256.0f);
                float var = S2 * (1.0f / 256.0f) - mean * mean;
                float rstd = rsqrtf(var + 1e-5f);
#pragma unroll
                for (int j = 0; j < 4; ++j) {
                    int nl = wn * 64 + j * 16 + l15;
                    float z = (v[i][j][reg] - mean) * rstd * bias1[nl] + aux0[nl];
                    out0[(size_t)(bm + row) * 256 + nl] = z;
                }
            }
        return;
    }

    // ---- staged epilogue: 4 rounds of 64-col chunks ----
#pragma unroll 1
    for (int jq = 0; jq < 4; ++jq) {
        __syncthreads();
        if (wn == jq) {
#pragma unroll
            for (int i = 0; i < 2; ++i)
#pragma unroll
                for (int j = 0; j < 4; ++j)
#pragma unroll
                    for (int reg = 0; reg < 4; ++reg)
                        Et[wm * 32 + i * 16 + l4 * 4 + reg][j * 16 + l15] = v[i][j][reg];
        }
        __syncthreads();

        if (mode == 1) {
            size_t base = (((size_t)t * H_ + jq) * NRG_ + rb) * DH_;
            float* of = bxi ? out1 : out0;
#pragma unroll
            for (int it = 0; it < 2; ++it) {
                int slot = it * 512 + tid;
                int row = slot >> 4, c4 = (slot & 15) * 4;
                *(f32x4*)(of + base + row * 64 + c4) = *(f32x4*)&Et[row][c4];
            }
            if (!bxi) {
#pragma unroll
                for (int it = 0; it < 2; ++it) {
                    int slot = it * 512 + tid;
                    int row = slot >> 4, c4 = (slot & 15) * 4;
                    uint2 u = make_uint2(pk2(Et[row][c4], Et[row][c4 + 1]),
                                         pk2(Et[row][c4 + 2], Et[row][c4 + 3]));
                    *(uint2*)(out2 + base + row * 64 + c4) = u;
                }
            } else {
                __syncthreads();
                if (wn == jq) {
#pragma unroll
                    for (int i = 0; i < 2; ++i)
#pragma unroll
                        for (int j = 0; j < 4; ++j)
#pragma unroll
                            for (int reg = 0; reg < 4; ++reg)
                                Et[j * 16 + l15][wm * 32 + i * 16 + l4 * 4 + reg] = v[i][j][reg];
                }
                __syncthreads();
                size_t tb = ((size_t)t * H_ + jq) * DH_ * NRG_;
#pragma unroll
                for (int it = 0; it < 2; ++it) {
                    int slot = it * 512 + tid;
                    int d = slot >> 4, r4 = (slot & 15) * 4;
                    uint2 u = make_uint2(pk2(Et[d][r4], Et[d][r4 + 1]),
                                         pk2(Et[d][r4 + 2], Et[d][r4 + 3]));
                    *(uint2*)(out3 + tb + (size_t)d * NRG_ + rb + r4) = u;
                }
            }
        } else if (mode == 2) {
            size_t base = (((size_t)t * H_ + jq) * NA_ + a0) * DH_;
#pragma unroll
            for (int it = 0; it < 2; ++it) {
                int slot = it * 512 + tid;
                int row = slot >> 4, c4 = (slot & 15) * 4;
                *(f32x4*)(out0 + base + row * 64 + c4) = *(f32x4*)&Et[row][c4];
                uint2 u = make_uint2(pk2(Et[row][c4] * 0.5f, Et[row][c4 + 1] * 0.5f),
                                     pk2(Et[row][c4 + 2] * 0.5f, Et[row][c4 + 3] * 0.5f));
                *(uint2*)(out2 + base + row * 64 + c4) = u;
            }
        } else {  // mode 0 / 3: bf16 row-major
#pragma unroll
            for (int it = 0; it < 2; ++it) {
                int slot = it * 512 + tid;
                int row = slot >> 4, c4 = (slot & 15) * 4;
                uint2 u = make_uint2(pk2(Et[row][c4], Et[row][c4 + 1]),
                                     pk2(Et[row][c4 + 2], Et[row][c4 + 3]));
                *(uint2*)(out2 + (size_t)(bm + row) * N + bn + jq * 64 + c4) = u;
            }
        }
    }
}

// ---------------------------------------------------------------------------
// Flash attention v3: ONE block per (t,h), 512 threads / 8 waves.
// Wave w owns a-rows [w*16, w*16+16). K/V/Q/cm each fetched exactly once.
// No online max (Q,K >= 0, e in [0,~1]); masked -> P_EPS.
// ---------------------------------------------------------------------------
__global__ __launch_bounds__(512) void attn_flash(
    const ushort* __restrict__ Qb, const ushort* __restrict__ Kb,
    const ushort* __restrict__ Vtb, const unsigned* __restrict__ cm,
    ushort* __restrict__ Y1b) {
    int th = blockIdx.x;
    int t = th >> 2, h = th & 3;
    int tid = threadIdx.x;
    int w = tid >> 6, lane = tid & 63;
    int l15 = lane & 15, l4 = lane >> 4;

    __shared__ ushort Ks[64][72];
    __shared__ ushort Vts[64][72];
    __shared__ ushort Ps[128][72];
    __shared__ unsigned cmw[128][2];

    bf16x8 qf[2];
#pragma unroll
    for (int kk = 0; kk < 2; ++kk)
        qf[kk] = *(const bf16x8*)(Qb + ((size_t)th * NA_ + w * 16 + l15) * DH_
                                  + kk * 32 + l4 * 8);

    f32x4 o[4];
    float rsum[4] = {0.0f, 0.0f, 0.0f, 0.0f};
#pragma unroll
    for (int ds = 0; ds < 4; ++ds)
#pragma unroll
        for (int r = 0; r < 4; ++r) o[ds][r] = 0.0f;

    for (int rt = 0; rt < 16; ++rt) {
        int r0 = rt * 64;
        {
            int row = tid >> 3, c8 = (tid & 7) * 8;
            *(bf16x8*)&Ks[row][c8] =
                *(const bf16x8*)(Kb + ((size_t)th * NRG_ + r0 + row) * DH_ + c8);
            *(bf16x8*)&Vts[row][c8] =
                *(const bf16x8*)(Vtb + ((size_t)th * DH_ + row) * NRG_ + r0 + c8);
        }
        if (tid < 256) {
            int a = tid >> 1, wd = tid & 1;
            cmw[a][wd] = cm[((size_t)t * NA_ + a) * 32 + rt * 2 + wd];
        }
        __syncthreads();

        f32x4 e[4];
#pragma unroll
        for (int rs = 0; rs < 4; ++rs) {
#pragma unroll
            for (int r = 0; r < 4; ++r) e[rs][r] = 0.0f;
#pragma unroll
            for (int kk = 0; kk < 2; ++kk) {
                bf16x8 kf = *(const bf16x8*)&Ks[rs * 16 + l15][kk * 32 + l4 * 8];
                e[rs] = __builtin_amdgcn_mfma_f32_16x16x32_bf16(qf[kk], kf, e[rs], 0, 0, 0);
            }
        }

#pragma unroll
        for (int reg = 0; reg < 4; ++reg) {
            int a_loc = w * 16 + l4 * 4 + reg;
            unsigned w0 = cmw[a_loc][0], w1 = cmw[a_loc][1];
#pragma unroll
            for (int rs = 0; rs < 4; ++rs) {
                unsigned wd = (rs & 2) ? w1 : w0;
                int bit = (wd >> ((rs & 1) * 16 + l15)) & 1;
                float p = bit ? __expf(e[rs][reg]) : P_EPS;
                rsum[reg] += p;
                Ps[a_loc][rs * 16 + l15] = f2bf(p);
            }
        }

#pragma unroll
        for (int rc = 0; rc < 2; ++rc) {
            bf16x8 pa = *(const bf16x8*)&Ps[w * 16 + l15][rc * 32 + l4 * 8];
#pragma unroll
            for (int ds = 0; ds < 4; ++ds) {
                bf16x8 vf = *(const bf16x8*)&Vts[ds * 16 + l15][rc * 32 + l4 * 8];
                o[ds] = __builtin_amdgcn_mfma_f32_16x16x32_bf16(pa, vf, o[ds], 0, 0, 0);
            }
        }
        __syncthreads();
    }

#pragma unroll
    for (int off = 1; off < 16; off <<= 1)
#pragma unroll
        for (int reg = 0; reg < 4; ++reg)
            rsum[reg] += __shfl_xor(rsum[reg], off);
    float rinv[4];
#pragma unroll
    for (int reg = 0; reg < 4; ++reg) rinv[reg] = 1.0f / rsum[reg];

#pragma unroll
    for (int ds = 0; ds < 4; ++ds)
#pragma unroll
        for (int reg = 0; reg < 4; ++reg) {
            int a_g = w * 16 + l4 * 4 + reg;
            int d = ds * 16 + l15;
            Y1b[((size_t)a_g * T_ + t) * D_ + h * DH_ + d] = f2bf(o[ds][reg] * rinv[reg]);
        }
}

// ---------------------------------------------------------------------------
extern "C" void kernel_launch(void* const* d_in, const int* in_sizes, int n_in,
                              void* d_out, int out_size, void* d_ws, size_t ws_size,
                              hipStream_t stream) {
    const float* agent   = (const float*)d_in[0];
    const float* rg      = (const float*)d_in[1];
    const float* ln_x_g  = (const float*)d_in[2];
    const float* ln_x_b  = (const float*)d_in[3];
    const float* wk      = (const float*)d_in[4];
    const float* bk      = (const float*)d_in[5];
    const float* wv      = (const float*)d_in[6];
    const float* bv      = (const float*)d_in[7];
    const float* wq      = (const float*)d_in[8];
    const float* bq      = (const float*)d_in[9];
    const float* q_scale = (const float*)d_in[10];
    const float* wy      = (const float*)d_in[11];
    const float* by      = (const float*)d_in[12];
    const float* wf1     = (const float*)d_in[13];
    const float* bf1     = (const float*)d_in[14];
    const float* wf2     = (const float*)d_in[15];
    const float* bf2     = (const float*)d_in[16];
    const float* ln_z_g  = (const float*)d_in[17];
    const float* ln_z_b  = (const float*)d_in[18];
    const int*   am      = (const int*)d_in[19];
    const int*   pm      = (const int*)d_in[20];
    const int*   vmk     = (const int*)d_in[21];

    float* Z  = (float*)d_out;
    float* Qp = Z + (size_t)NA_ * T_ * D_;
    float* Kp = Qp + (size_t)NA_ * T_ * D_;
    float* Vp = Kp + (size_t)NRG_ * T_ * D_;

    char* p = (char*)d_ws;
    ushort* rgn_b = (ushort*)p;   p += (size_t)NRG_ * T_ * D_ * 2;   // aliased by F1b
    ushort* agn_b = (ushort*)p;   p += (size_t)NA_ * T_ * D_ * 2;
    ushort* wkvt  = (ushort*)p;   p += (size_t)512 * 256 * 2;
    ushort* wqt   = (ushort*)p;   p += (size_t)256 * 256 * 2;
    ushort* wyt   = (ushort*)p;   p += (size_t)256 * 256 * 2;
    ushort* wf1t  = (ushort*)p;   p += (size_t)1024 * 256 * 2;
    ushort* wf2t  = (ushort*)p;   p += (size_t)256 * 1024 * 2;
    unsigned* cm  = (unsigned*)p; p += (size_t)T_ * NA_ * 32 * 4;
    ushort* Kb    = (ushort*)p;   p += (size_t)T_ * H_ * NRG_ * DH_ * 2;
    ushort* Vtb   = (ushort*)p;   p += (size_t)T_ * H_ * NRG_ * DH_ * 2;
    ushort* Qb    = (ushort*)p;   p += (size_t)T_ * H_ * NA_ * DH_ * 2;
    ushort* Y1b   = (ushort*)p;   p += (size_t)NA_ * T_ * D_ * 2;
    ushort* Sb    = (ushort*)p;   p += (size_t)NA_ * T_ * D_ * 2;

    ushort* F1b = rgn_b;          // alias: rgn dead after KV/Q GEMMs

    dim3 blk(256), wblk(512);

    ln_norm<<<dim3((NA_ + NRG_) * T_ / 4), blk, 0, stream>>>(
        agent, rg, ln_x_g, ln_x_b, agn_b, rgn_b);

    prep_w_all<<<dim3(3072), blk, 0, stream>>>(
        wk, wv, wq, wy, wf1, wf2, wkvt, wqt, wyt, wf1t, wf2t);

    pack_mask<<<dim3(T_ * NA_ / 4), blk, 0, stream>>>(am, pm, vmk, cm);

    // K|V fused (t-major M), XCD-paired 1D grid: 2912 = 182*16
    gemm_wide<<<dim3(T_ * 32), wblk, 0, stream>>>(
        rgn_b, wkvt, bk, bv, nullptr, nullptr,
        Kp, Vp, Kb, Vtb, 512, 256, 1);

    // Q (t-major M): grid (1, 91*2)
    gemm_wide<<<dim3(1, T_ * 2), wblk, 0, stream>>>(
        agn_b, wqt, bq, nullptr, q_scale, nullptr,
        Qp, nullptr, Qb, nullptr, 256, 256, 2);

    attn_flash<<<dim3(T_ * H_), wblk, 0, stream>>>(Qb, Kb, Vtb, cm, Y1b);

    // S = relu(Y1 @ wy + by) + agent_n
    gemm_wide<<<dim3(1, NA_ * T_ / 64), wblk, 0, stream>>>(
        Y1b, wyt, by, nullptr, nullptr, agn_b,
        nullptr, nullptr, Sb, nullptr, 256, 256, 3);

    // F1 = relu(S @ wf1 + bf1)
    gemm_wide<<<dim3(4, NA_ * T_ / 64), wblk, 0, stream>>>(
        Sb, wf1t, bf1, nullptr, nullptr, nullptr,
        nullptr, nullptr, F1b, nullptr, 1024, 256, 0);

    // Z = ln(relu(F1 @ wf2 + bf2))
    gemm_wide<<<dim3(1, NA_ * T_ / 64), wblk, 0, stream>>>(
        F1b, wf2t, bf2, ln_z_g, ln_z_b, nullptr,
        Z, nullptr, nullptr, nullptr, 256, 1024, 5);
}